// Round 10
// baseline (568.507 us; speedup 1.0000x reference)
//
#include <hip/hip_runtime.h>
#include <math.h>

// Problem constants
#define BN 16
#define HWSZ 16384
#define NC 80
#define KK 100

typedef _Float16 f16;
typedef _Float16 f16x2 __attribute__((ext_vector_type(2)));
typedef _Float16 f16x4 __attribute__((ext_vector_type(4)));
typedef _Float16 f16x8 __attribute__((ext_vector_type(8)));
typedef float    f32x4 __attribute__((ext_vector_type(4)));
typedef unsigned int uint;
typedef unsigned long long u64;

// ---- workspace layout (float units) ----
#define WS_CLS   0
#define CLS_SZ   (BN*NC*HWSZ)
#define WS_REG   (WS_CLS + CLS_SZ)
#define REG_SZ   (BN*2*HWSZ)
#define WS_WH    (WS_REG + REG_SZ)
#define WH_SZ    (BN*2*HWSZ)
#define WS_SC    (WS_WH + WH_SZ)
#define SC_SZ    (BN*HWSZ)
#define WS_CAT   (WS_SC + SC_SZ)
#define CAT_SZ   (BN*HWSZ)
#define WS_W1H   (WS_CAT + CAT_SZ)             // f16 3*9*64*64 -> 55296 floats/plane
#define W1F      (110592/2)
#define WS_W1L   (WS_W1H + W1F)
#define WS_W2H   (WS_W1L + W1F)                // f16 112*64 (padded) -> 3584 floats/plane
#define W2F      (7168/2)
#define WS_W2L   (WS_W2H + W2F)
// Pre-split/pre-transposed x in (swizzled) LDS-image layout.
// Region = (b,gy,h,chunk): 66 rows x 32ci f16 = 2112 f16 = 4224 B.
#define NREG     (BN*128*2*2)                  // 8192 regions
#define WS_XTH   (WS_W2L + W2F)
#define XT_F     (NREG*2112/2)
#define WS_XTL   (WS_XTH + XT_F)
#define WS_ZR    (WS_XTL + XT_F)               // 4224 B zero region (f16)
#define ZR_F     1056
// partial peak buffers for class-split k_peaks (quarters 1..3)
#define WS_SC1   (WS_ZR + ZR_F)
#define WS_CAT1  (WS_SC1 + SC_SZ)
#define WS_SC2   (WS_CAT1 + CAT_SZ)
#define WS_CAT2  (WS_SC2 + SC_SZ)
#define WS_SC3   (WS_CAT2 + CAT_SZ)
#define WS_CAT3  (WS_SC3 + SC_SZ)
#define WS_END4  (WS_CAT3 + CAT_SZ)

// scaling: x*16, w*256 -> acc = 4096*true
#define SCL_X   16.0f
#define SCL_W   256.0f
#define INV_ACC (1.0f/4096.0f)

// async global->LDS, 16B per lane (dest = wave-uniform base + lane*16)
#define GL2LDS(g, l) __builtin_amdgcn_global_load_lds( \
    (__attribute__((address_space(1))) unsigned int*)(unsigned long long)(const void*)(g), \
    (__attribute__((address_space(3))) unsigned int*)(unsigned int)(unsigned long long)(void*)(l), \
    16, 0, 0)

// ---------------------------------------------------------------------------
// Prep: split weights to fp16 hi/lo (scaled by 256); zero the zero-region.
// ---------------------------------------------------------------------------
__global__ void k_prep(const float* __restrict__ cw1, const float* __restrict__ rw1,
                       const float* __restrict__ ww1, const float* __restrict__ cw2,
                       const float* __restrict__ rw2, const float* __restrict__ ww2,
                       f16* __restrict__ w1h, f16* __restrict__ w1l,
                       f16* __restrict__ w2h, f16* __restrict__ w2l,
                       float* __restrict__ zr) {
    int idx = blockIdx.x * 256 + threadIdx.x;
    if (idx < 3*9*64*64) {
        int ci = idx & 63, co = (idx >> 6) & 63;
        int s  = (idx >> 12) % 9, br = idx / 36864;
        const float* src = (br == 0) ? cw1 : (br == 1 ? rw1 : ww1);
        float v = src[(co*64 + ci)*9 + s] * SCL_W;
        f16 h = (f16)v;
        w1h[idx] = h; w1l[idx] = (f16)(v - (float)h);
    }
    int j = idx - 3*9*64*64;
    if (j >= 0 && j < 112*64) {
        int ci = j & 63, row = j >> 6;
        float v = 0.f;
        if (row < 80)                    v = cw2[row*64 + ci];
        else if (row < 82)               v = rw2[(row-80)*64 + ci];
        else if (row >= 96 && row < 98)  v = ww2[(row-96)*64 + ci];
        v *= SCL_W;
        f16 h = (f16)v;
        w2h[j] = h; w2l[j] = (f16)(v - (float)h);
    }
    if (zr && idx < ZR_F) zr[idx] = 0.f;
}

// ---------------------------------------------------------------------------
// Pre-split + pre-transpose x into per-(b,gy,h,chunk) regions, with the 16B
// slot swizzle baked into the GLOBAL layout.
// ---------------------------------------------------------------------------
__global__ __launch_bounds__(256) void k_prepx(const float* __restrict__ x,
                                               f16* __restrict__ xth,
                                               f16* __restrict__ xtl) {
    const int reg = blockIdx.x;
    const int chunk = reg & 1, hh = (reg >> 1) & 1;
    const int gy = (reg >> 2) & 127, b = reg >> 9;
    __shared__ f16 th[66*72] __attribute__((aligned(16)));
    __shared__ f16 tl[66*72] __attribute__((aligned(16)));
    const int tid = threadIdx.x;
    const float* xb = x + ((size_t)(b*64 + chunk*32))*HWSZ + gy*128;
    #pragma unroll
    for (int it = 0; it < 9; it++) {
        int idx = it*256 + tid;
        if (idx < 2112) {
            int ci = idx / 66, pxi = idx - ci*66;
            int gp = hh*64 - 1 + pxi;
            float v = 0.f;
            if (gp >= 0 && gp < 128) v = xb[(size_t)ci*HWSZ + gp] * SCL_X;
            f16 hv = (f16)v;
            th[pxi*72 + ci] = hv;
            tl[pxi*72 + ci] = (f16)(v - (float)hv);
        }
    }
    __syncthreads();
    f16* oh = xth + (size_t)reg*2112;
    f16* ol = xtl + (size_t)reg*2112;
    {
        int row = tid >> 2, q = tid & 3;
        int sq = q ^ ((row >> 1) & 3);
        *(f16x8*)(oh + row*32 + sq*8) = *(const f16x8*)(th + row*72 + q*8);
        *(f16x8*)(ol + row*32 + sq*8) = *(const f16x8*)(tl + row*72 + q*8);
        if (tid < 8) {
            int u2 = 256 + tid, row2 = u2 >> 2, q2 = u2 & 3;
            int sq2 = q2 ^ ((row2 >> 1) & 3);
            *(f16x8*)(oh + row2*32 + sq2*8) = *(const f16x8*)(th + row2*72 + q2*8);
            *(f16x8*)(ol + row2*32 + sq2*8) = *(const f16x8*)(tl + row2*72 + q2*8);
        }
    }
}

// ---------------------------------------------------------------------------
// r20: branch-split conv.  r14/r18/r19 showed the 96-AGPR 3-branch
// accumulator leaves zero register headroom at any occupancy >2 waves/SIMD.
// Split: k_conv_c (cls only, acc 32) at (256,4); k_conv_rw (reg+wh, acc 64)
// at (256,3).  Inner loop per accumulator is r17's verified code verbatim
// -> bit-identical.  xt staged twice (L3-hot second time); w1 reads split.
// ---------------------------------------------------------------------------
#define ABUF 8448                    // bytes per A buffer (hi 4224 + lo 4224)

// common prologue macro: block index swizzle (2048 blocks, %8==0)
#define CONV_IDX() \
    const int p  = blockIdx.x + 2*blockIdx.y + 128*blockIdx.z;               \
    const int lg = (p & 7)*256 + (p >> 3);                                   \
    const int b  = lg >> 7;                                                  \
    const int y0 = ((lg & 127) >> 1) * 2;                                    \
    const int h  = lg & 1;                                                   \
    const int tid = threadIdx.x;                                             \
    const int w = tid >> 6, lane = tid & 63;                                 \
    const int l15 = lane & 15, quad = lane >> 4;                             \
    const int co = w*16 + l15;

#define STAGE4(ch) do {                                                       \
    _Pragma("unroll")                                                         \
    for (int gyi = 0; gyi < 4; gyi++) {                                       \
        const int gy_ = y0 - 1 + gyi;                                         \
        const f16* sh_; const f16* sl_;                                       \
        if (gy_ >= 0 && gy_ < 128) {                                          \
            size_t ro_ = (size_t)(((b*128 + gy_)*2 + h)*2 + (ch)) * 2112;     \
            sh_ = xth + ro_; sl_ = xtl + ro_;                                 \
        } else { sh_ = zreg; sl_ = zreg; }                                    \
        char* db_ = smem + gyi*ABUF;                                          \
        GL2LDS(sh_ + tid*8, db_ + tid*16);                                    \
        GL2LDS(sl_ + tid*8, db_ + 4224 + tid*16);                             \
        if (tid < 8) {                                                        \
            GL2LDS(sh_ + 2048 + tid*8, db_ + 4096 + tid*16);                  \
            GL2LDS(sl_ + 2048 + tid*8, db_ + 4224 + 4096 + tid*16);           \
        }                                                                     \
    }                                                                         \
} while (0)

// ============================ cls-only conv ================================
__global__ __launch_bounds__(256, 4) void k_conv_c(
    const f16* __restrict__ xth, const f16* __restrict__ xtl, const f16* __restrict__ zreg,
    const f16* __restrict__ w1h, const f16* __restrict__ w1l,
    const f16* __restrict__ w2h, const f16* __restrict__ w2l,
    const float* __restrict__ b1c, const float* __restrict__ b2c,
    float* __restrict__ cls_o)
{
    __shared__ char smem[4*ABUF] __attribute__((aligned(16)));   // 33792 B
    f16* Rh = (f16*)smem;
    f16* Rl = (f16*)(smem + 9216);
    CONV_IDX();

    f32x4 accA[4], accB[4];
    #pragma unroll
    for (int m = 0; m < 4; m++) {
        accA[m] = (f32x4){0.f,0.f,0.f,0.f};
        accB[m] = (f32x4){0.f,0.f,0.f,0.f};
    }

    #define COMPUTE_C(ph) do {                                                \
        for (int r = 0; r < 3; r++) {                                         \
            const f16* A0 = (const f16*)(smem + r*ABUF);                      \
            const f16* A1 = (const f16*)(smem + (r+1)*ABUF);                  \
            _Pragma("unroll")                                                 \
            for (int dx = 0; dx < 3; dx++) {                                  \
                const int s = r*3 + dx;                                       \
                size_t k = ((size_t)(s*64 + co))*64 + (ph)*32 + quad*8;       \
                f16x8 bh = *(const f16x8*)(w1h + k);                          \
                f16x8 bl = *(const f16x8*)(w1l + k);                          \
                _Pragma("unroll")                                             \
                for (int m = 0; m < 4; m++) {                                 \
                    const int row = m*16 + l15 + dx;                          \
                    const int off = row*32 + ((quad ^ ((row >> 1) & 3)) << 3);\
                    {                                                         \
                        f16x8 ah0 = *(const f16x8*)(A0 + off);                \
                        f16x8 al0 = *(const f16x8*)(A0 + 2112 + off);         \
                        accA[m] = __builtin_amdgcn_mfma_f32_16x16x32_f16(ah0, bh, accA[m], 0,0,0); \
                        accA[m] = __builtin_amdgcn_mfma_f32_16x16x32_f16(ah0, bl, accA[m], 0,0,0); \
                        accA[m] = __builtin_amdgcn_mfma_f32_16x16x32_f16(al0, bh, accA[m], 0,0,0); \
                    }                                                         \
                    {                                                         \
                        f16x8 ah1 = *(const f16x8*)(A1 + off);                \
                        f16x8 al1 = *(const f16x8*)(A1 + 2112 + off);         \
                        accB[m] = __builtin_amdgcn_mfma_f32_16x16x32_f16(ah1, bh, accB[m], 0,0,0); \
                        accB[m] = __builtin_amdgcn_mfma_f32_16x16x32_f16(ah1, bl, accB[m], 0,0,0); \
                        accB[m] = __builtin_amdgcn_mfma_f32_16x16x32_f16(al1, bh, accB[m], 0,0,0); \
                    }                                                         \
                }                                                             \
            }                                                                 \
        }                                                                     \
    } while (0)

    STAGE4(0);
    __syncthreads();
    COMPUTE_C(0);
    __syncthreads();
    STAGE4(1);
    __syncthreads();
    COMPUTE_C(1);
    #undef COMPUTE_C

    const float b1v = b1c[co];
    #define EPIROW_C(ACC, yy) do {                                            \
        __syncthreads();                                                      \
        _Pragma("unroll")                                                     \
        for (int m = 0; m < 4; m++)                                           \
            _Pragma("unroll")                                                 \
            for (int rg = 0; rg < 4; rg++) {                                  \
                float t = fmaxf(ACC[m][rg]*INV_ACC + b1v, 0.f) * SCL_X;       \
                f16 hh = (f16)t;                                              \
                int pxl = m*16 + quad*4 + rg;                                 \
                Rh[pxl*72 + co] = hh;                                         \
                Rl[pxl*72 + co] = (f16)(t - (float)hh);                       \
            }                                                                 \
        __syncthreads();                                                      \
        f32x4 a2[5];                                                          \
        _Pragma("unroll")                                                     \
        for (int n = 0; n < 5; n++) a2[n] = (f32x4){0.f,0.f,0.f,0.f};         \
        _Pragma("unroll")                                                     \
        for (int kc = 0; kc < 64; kc += 32) {                                 \
            int off = co*72 + kc + quad*8;                                    \
            f16x8 xh = *(const f16x8*)(Rh + off);                             \
            f16x8 xl = *(const f16x8*)(Rl + off);                             \
            _Pragma("unroll")                                                 \
            for (int n = 0; n < 5; n++) {                                     \
                const f16* g2h = w2h + (n*16 + l15)*64 + kc + quad*8;         \
                const f16* g2l = w2l + (n*16 + l15)*64 + kc + quad*8;         \
                f16x8 bh2 = *(const f16x8*)g2h;                               \
                f16x8 bl2 = *(const f16x8*)g2l;                               \
                a2[n] = __builtin_amdgcn_mfma_f32_16x16x32_f16(xh, bh2, a2[n], 0,0,0); \
                a2[n] = __builtin_amdgcn_mfma_f32_16x16x32_f16(xh, bl2, a2[n], 0,0,0); \
                a2[n] = __builtin_amdgcn_mfma_f32_16x16x32_f16(xl, bh2, a2[n], 0,0,0); \
            }                                                                 \
        }                                                                     \
        const int pxg = h*64 + w*16 + quad*4;                                 \
        _Pragma("unroll")                                                     \
        for (int n = 0; n < 5; n++) {                                         \
            int co2 = n*16 + l15;                                             \
            float bb = b2c[co2];                                              \
            _Pragma("unroll")                                                 \
            for (int rg = 0; rg < 4; rg++) {                                  \
                float sv = a2[n][rg]*INV_ACC + bb;                            \
                cls_o[((size_t)(b*80 + co2)*128 + (yy))*128 + pxg + rg] = 1.f/(1.f + expf(-sv)); \
            }                                                                 \
        }                                                                     \
    } while (0)

    EPIROW_C(accA, y0);
    EPIROW_C(accB, y0 + 1);
    #undef EPIROW_C
}

// ============================ reg+wh conv ==================================
__global__ __launch_bounds__(256, 3) void k_conv_rw(
    const f16* __restrict__ xth, const f16* __restrict__ xtl, const f16* __restrict__ zreg,
    const f16* __restrict__ w1h, const f16* __restrict__ w1l,
    const f16* __restrict__ w2h, const f16* __restrict__ w2l,
    const float* __restrict__ b1r, const float* __restrict__ b1w,
    const float* __restrict__ b2r, const float* __restrict__ b2w,
    float* __restrict__ reg_o, float* __restrict__ wh_o)
{
    __shared__ char smem[4*ABUF] __attribute__((aligned(16)));   // 33792 B
    f16* Rh = (f16*)smem;
    f16* Rl = (f16*)(smem + 9216);
    CONV_IDX();

    f32x4 accA[2][4], accB[2][4];
    #pragma unroll
    for (int q = 0; q < 2; q++)
        #pragma unroll
        for (int m = 0; m < 4; m++) {
            accA[q][m] = (f32x4){0.f,0.f,0.f,0.f};
            accB[q][m] = (f32x4){0.f,0.f,0.f,0.f};
        }

    #define COMPUTE_RW(ph) do {                                               \
        for (int r = 0; r < 3; r++) {                                         \
            const f16* A0 = (const f16*)(smem + r*ABUF);                      \
            const f16* A1 = (const f16*)(smem + (r+1)*ABUF);                  \
            _Pragma("unroll")                                                 \
            for (int dx = 0; dx < 3; dx++) {                                  \
                const int s = r*3 + dx;                                       \
                f16x8 bh[2], bl[2];                                           \
                _Pragma("unroll")                                             \
                for (int q2 = 0; q2 < 2; q2++) {                              \
                    size_t k = ((size_t)(((q2+1)*9 + s)*64 + co))*64 + (ph)*32 + quad*8; \
                    bh[q2] = *(const f16x8*)(w1h + k);                        \
                    bl[q2] = *(const f16x8*)(w1l + k);                        \
                }                                                             \
                _Pragma("unroll")                                             \
                for (int m = 0; m < 4; m++) {                                 \
                    const int row = m*16 + l15 + dx;                          \
                    const int off = row*32 + ((quad ^ ((row >> 1) & 3)) << 3);\
                    {                                                         \
                        f16x8 ah0 = *(const f16x8*)(A0 + off);                \
                        f16x8 al0 = *(const f16x8*)(A0 + 2112 + off);         \
                        _Pragma("unroll")                                     \
                        for (int q2 = 0; q2 < 2; q2++) {                      \
                            accA[q2][m] = __builtin_amdgcn_mfma_f32_16x16x32_f16(ah0, bh[q2], accA[q2][m], 0,0,0); \
                            accA[q2][m] = __builtin_amdgcn_mfma_f32_16x16x32_f16(ah0, bl[q2], accA[q2][m], 0,0,0); \
                            accA[q2][m] = __builtin_amdgcn_mfma_f32_16x16x32_f16(al0, bh[q2], accA[q2][m], 0,0,0); \
                        }                                                     \
                    }                                                         \
                    {                                                         \
                        f16x8 ah1 = *(const f16x8*)(A1 + off);                \
                        f16x8 al1 = *(const f16x8*)(A1 + 2112 + off);         \
                        _Pragma("unroll")                                     \
                        for (int q2 = 0; q2 < 2; q2++) {                      \
                            accB[q2][m] = __builtin_amdgcn_mfma_f32_16x16x32_f16(ah1, bh[q2], accB[q2][m], 0,0,0); \
                            accB[q2][m] = __builtin_amdgcn_mfma_f32_16x16x32_f16(ah1, bl[q2], accB[q2][m], 0,0,0); \
                            accB[q2][m] = __builtin_amdgcn_mfma_f32_16x16x32_f16(al1, bh[q2], accB[q2][m], 0,0,0); \
                        }                                                     \
                    }                                                         \
                }                                                             \
            }                                                                 \
        }                                                                     \
    } while (0)

    STAGE4(0);
    __syncthreads();
    COMPUTE_RW(0);
    __syncthreads();
    STAGE4(1);
    __syncthreads();
    COMPUTE_RW(1);
    #undef COMPUTE_RW

    // epilogue: br = 1 (reg) then 2 (wh); unrolled -> static acc indices
    #define EPIROW_RW(ACC, yy) do {                                           \
        __syncthreads();                                                      \
        _Pragma("unroll")                                                     \
        for (int m = 0; m < 4; m++)                                           \
            _Pragma("unroll")                                                 \
            for (int rg = 0; rg < 4; rg++) {                                  \
                float t = fmaxf(ACC[br-1][m][rg]*INV_ACC + b1v, 0.f) * SCL_X; \
                f16 hh = (f16)t;                                              \
                int pxl = m*16 + quad*4 + rg;                                 \
                Rh[pxl*72 + co] = hh;                                         \
                Rl[pxl*72 + co] = (f16)(t - (float)hh);                       \
            }                                                                 \
        __syncthreads();                                                      \
        f32x4 a2 = (f32x4){0.f,0.f,0.f,0.f};                                  \
        _Pragma("unroll")                                                     \
        for (int kc = 0; kc < 64; kc += 32) {                                 \
            int off = co*72 + kc + quad*8;                                    \
            f16x8 xh = *(const f16x8*)(Rh + off);                             \
            f16x8 xl = *(const f16x8*)(Rl + off);                             \
            const f16* g2h = w2h + (rowoff + l15)*64 + kc + quad*8;           \
            const f16* g2l = w2l + (rowoff + l15)*64 + kc + quad*8;           \
            f16x8 bh2 = *(const f16x8*)g2h;                                   \
            f16x8 bl2 = *(const f16x8*)g2l;                                   \
            a2 = __builtin_amdgcn_mfma_f32_16x16x32_f16(xh, bh2, a2, 0,0,0);  \
            a2 = __builtin_amdgcn_mfma_f32_16x16x32_f16(xh, bl2, a2, 0,0,0);  \
            a2 = __builtin_amdgcn_mfma_f32_16x16x32_f16(xl, bh2, a2, 0,0,0);  \
        }                                                                     \
        const int pxg = h*64 + w*16 + quad*4;                                 \
        if (l15 < 2) {                                                        \
            float bb = b2[l15];                                               \
            _Pragma("unroll")                                                 \
            for (int rg = 0; rg < 4; rg++) {                                  \
                float sv = a2[rg]*INV_ACC + bb;                               \
                float o  = (br == 1) ? (1.f/(1.f + expf(-sv))) : expf(sv);    \
                outp[((size_t)(b*2 + l15))*HWSZ + (yy)*128 + pxg + rg] = o;   \
            }                                                                 \
        }                                                                     \
    } while (0)

    #pragma unroll
    for (int br = 1; br <= 2; br++) {
        const float* b1 = (br == 1) ? b1r : b1w;
        const float* b2 = (br == 1) ? b2r : b2w;
        float* outp     = (br == 1) ? reg_o : wh_o;
        const int rowoff = (br == 1) ? 80 : 96;
        const float b1v = b1[co];
        EPIROW_RW(accA, y0);
        EPIROW_RW(accB, y0 + 1);
    }
    #undef EPIROW_RW
}

// ---------------------------------------------------------------------------
// Fallback conv (r11 kernel) — used only if ws_size can't hold the pre-split
// x planes.  Bit-identical outputs.
// ---------------------------------------------------------------------------
#define A_STRIDE 36
#define ABUF_FB  9504
__global__ __launch_bounds__(256) void k_conv_fb(
    const float* __restrict__ x,
    const f16* __restrict__ w1h, const f16* __restrict__ w1l,
    const f16* __restrict__ w2h, const f16* __restrict__ w2l,
    const float* __restrict__ b1c, const float* __restrict__ b1r, const float* __restrict__ b1w,
    const float* __restrict__ b2c, const float* __restrict__ b2r, const float* __restrict__ b2w,
    float* __restrict__ cls_o, float* __restrict__ reg_o, float* __restrict__ wh_o)
{
    __shared__ char smem[19008] __attribute__((aligned(16)));
    f16* Rh = (f16*)smem;
    f16* Rl = (f16*)(smem + 9216);

    const int h = blockIdx.x, y = blockIdx.y, b = blockIdx.z;
    const int tid = threadIdx.x;
    const int w = tid >> 6, lane = tid & 63;
    const int l15 = lane & 15, quad = lane >> 4;

    static const int CS[6] = {0,0,0,1,1,1};
    static const int RS[6] = {0,1,2,0,1,2};

    #define STAGEF(bufi, si_) do {                                            \
        const int gy = y - 1 + RS[si_];                                       \
        const bool ok = (gy >= 0) && (gy < 128);                              \
        const float* xp = x + ((size_t)(b*64 + CS[si_]*32)*128 + gy)*128;     \
        f16x2* dh = (f16x2*)(smem + (bufi)*ABUF_FB);                          \
        f16x2* dl = (f16x2*)(smem + (bufi)*ABUF_FB + 4752);                   \
        _Pragma("unroll")                                                     \
        for (int e0 = 0; e0 < 1024; e0 += 256) {                              \
            int e = e0 + tid;                                                 \
            int pxl = e & 63, cp = e >> 6;                                    \
            float v0 = 0.f, v1 = 0.f;                                         \
            if (ok) { int g = h*64 + pxl;                                     \
                      v0 = xp[(size_t)(2*cp)*HWSZ + g]*SCL_X;                 \
                      v1 = xp[(size_t)(2*cp+1)*HWSZ + g]*SCL_X; }             \
            f16 h0 = (f16)v0, h1 = (f16)v1;                                   \
            f16 l0 = (f16)(v0 - (float)h0), l1 = (f16)(v1 - (float)h1);       \
            int wi = (pxl + 1)*18 + cp;                                       \
            dh[wi] = (f16x2){h0, h1};                                         \
            dl[wi] = (f16x2){l0, l1};                                         \
        }                                                                     \
        if (tid < 32) {                                                       \
            int side = tid >> 4, cp = tid & 15;                               \
            bool valid = ok && (side ? (h == 0) : (h == 1));                  \
            int g = side ? 64 : 63;                                           \
            float v0 = 0.f, v1 = 0.f;                                         \
            if (valid) { v0 = xp[(size_t)(2*cp)*HWSZ + g]*SCL_X;              \
                         v1 = xp[(size_t)(2*cp+1)*HWSZ + g]*SCL_X; }          \
            f16 h0 = (f16)v0, h1 = (f16)v1;                                   \
            f16 l0 = (f16)(v0 - (float)h0), l1 = (f16)(v1 - (float)h1);       \
            int wi = (side ? 65 : 0)*18 + cp;                                 \
            dh[wi] = (f16x2){h0, h1};                                         \
            dl[wi] = (f16x2){l0, l1};                                         \
        }                                                                     \
    } while (0)

    f32x4 acc[3][4];
    #pragma unroll
    for (int br = 0; br < 3; br++)
        #pragma unroll
        for (int m = 0; m < 4; m++) acc[br][m] = (f32x4){0.f,0.f,0.f,0.f};

    STAGEF(0, 0);
    __syncthreads();

    for (int si = 0; si < 6; si++) {
        const int cur = si & 1;
        if (si < 5) STAGEF(cur ^ 1, si + 1);
        const f16* APh = (const f16*)(smem + cur*ABUF_FB);
        const f16* APl = APh + 2376;
        const int chunk = CS[si], r = RS[si];
        #pragma unroll
        for (int dx = 0; dx < 3; dx++) {
            const int s = r*3 + dx;
            f16x8 bh[3], bl[3];
            #pragma unroll
            for (int br = 0; br < 3; br++) {
                size_t k = ((size_t)((br*9 + s)*64 + (w*16 + l15)))*64 + chunk*32 + quad*8;
                bh[br] = *(const f16x8*)(w1h + k);
                bl[br] = *(const f16x8*)(w1l + k);
            }
            #pragma unroll
            for (int m = 0; m < 4; m++) {
                int off = (m*16 + l15 + dx)*A_STRIDE + quad*8;
                f16x4 h0 = *(const f16x4*)(APh + off);
                f16x4 h1 = *(const f16x4*)(APh + off + 4);
                f16x4 u0 = *(const f16x4*)(APl + off);
                f16x4 u1 = *(const f16x4*)(APl + off + 4);
                f16x8 ah = __builtin_shufflevector(h0, h1, 0,1,2,3,4,5,6,7);
                f16x8 al = __builtin_shufflevector(u0, u1, 0,1,2,3,4,5,6,7);
                #pragma unroll
                for (int br = 0; br < 3; br++) {
                    acc[br][m] = __builtin_amdgcn_mfma_f32_16x16x32_f16(ah, bh[br], acc[br][m], 0,0,0);
                    acc[br][m] = __builtin_amdgcn_mfma_f32_16x16x32_f16(ah, bl[br], acc[br][m], 0,0,0);
                    acc[br][m] = __builtin_amdgcn_mfma_f32_16x16x32_f16(al, bh[br], acc[br][m], 0,0,0);
                }
            }
        }
        __syncthreads();
    }
    #undef STAGEF

    #pragma unroll
    for (int br = 0; br < 3; br++) {
        const float* b1 = (br == 0) ? b1c : (br == 1 ? b1r : b1w);
        const float b1v = b1[w*16 + l15];
        __syncthreads();
        #pragma unroll
        for (int m = 0; m < 4; m++)
            #pragma unroll
            for (int rg = 0; rg < 4; rg++) {
                float t = fmaxf(acc[br][m][rg]*INV_ACC + b1v, 0.f) * SCL_X;
                f16 hh = (f16)t;
                int pxl = m*16 + quad*4 + rg;
                int co  = w*16 + l15;
                Rh[pxl*72 + co] = hh;
                Rl[pxl*72 + co] = (f16)(t - (float)hh);
            }
        __syncthreads();

        const int NT     = (br == 0) ? 5 : 1;
        const int rowoff = (br == 0) ? 0 : (br == 1 ? 80 : 96);
        f32x4 a2[5];
        #pragma unroll
        for (int n = 0; n < 5; n++) a2[n] = (f32x4){0.f,0.f,0.f,0.f};

        #pragma unroll
        for (int kc = 0; kc < 64; kc += 32) {
            int off = (w*16 + l15)*72 + kc + quad*8;
            f16x8 xh = *(const f16x8*)(Rh + off);
            f16x8 xl = *(const f16x8*)(Rl + off);
            #pragma unroll
            for (int n = 0; n < 5; n++) {
                if (n >= NT) break;
                const f16* g2h = w2h + (rowoff + n*16 + l15)*64 + kc + quad*8;
                const f16* g2l = w2l + (rowoff + n*16 + l15)*64 + kc + quad*8;
                f16x8 bh = *(const f16x8*)g2h;
                f16x8 bl = *(const f16x8*)g2l;
                a2[n] = __builtin_amdgcn_mfma_f32_16x16x32_f16(xh, bh, a2[n], 0,0,0);
                a2[n] = __builtin_amdgcn_mfma_f32_16x16x32_f16(xh, bl, a2[n], 0,0,0);
                a2[n] = __builtin_amdgcn_mfma_f32_16x16x32_f16(xl, bh, a2[n], 0,0,0);
            }
        }

        const int pxg = h*64 + w*16 + quad*4;
        if (br == 0) {
            #pragma unroll
            for (int n = 0; n < 5; n++) {
                int co2 = n*16 + l15;
                float bb = b2c[co2];
                #pragma unroll
                for (int rg = 0; rg < 4; rg++) {
                    float sv = a2[n][rg]*INV_ACC + bb;
                    cls_o[((size_t)(b*80 + co2)*128 + y)*128 + pxg + rg] = 1.f/(1.f + expf(-sv));
                }
            }
        } else {
            if (l15 < 2) {
                const float* b2 = (br == 1) ? b2r : b2w;
                float* outp     = (br == 1) ? reg_o : wh_o;
                float bb = b2[l15];
                #pragma unroll
                for (int rg = 0; rg < 4; rg++) {
                    float sv = a2[0][rg]*INV_ACC + bb;
                    float o  = (br == 1) ? (1.f/(1.f + expf(-sv))) : expf(sv);
                    outp[((size_t)(b*2 + l15))*HWSZ + y*128 + pxg + rg] = o;
                }
            }
        }
    }
}

// ---------------------------------------------------------------------------
// 3x3 peak mask + max/argmax over a CLASS RANGE (4 rows per wave, verified
// r17).  blockIdx.z = class quarter (span 20); fallback: span 80, z=1.
// ---------------------------------------------------------------------------
__global__ __launch_bounds__(256) void k_peaks(const float* __restrict__ cls,
                                               float* __restrict__ scA, int* __restrict__ catA,
                                               float* __restrict__ scB, int* __restrict__ catB,
                                               float* __restrict__ scC, int* __restrict__ catC,
                                               float* __restrict__ scD, int* __restrict__ catD,
                                               int span) {
    const int b  = blockIdx.y;
    const int z  = blockIdx.z;
    const int c0 = z * span, c1 = c0 + span;
    float* __restrict__ sc  = (z == 0) ? scA  : (z == 1) ? scB  : (z == 2) ? scC  : scD;
    int*   __restrict__ cat = (z == 0) ? catA : (z == 1) ? catB : (z == 2) ? catC : catD;
    const int wv = threadIdx.x >> 6;
    const int l  = threadIdx.x & 63;
    const int y0 = blockIdx.x * 16 + wv * 4;    // rows y0 .. y0+3
    const int p0 = l * 2;
    const bool gt = (y0 > 0);
    const bool gb = (y0 + 4 < 128);
    float best[8]; int bc[8];
    #pragma unroll
    for (int i = 0; i < 8; i++) { best[i] = -1.f; bc[i] = c0; }
    for (int c = c0; c < c1; c++) {
        const float* pl = cls + (size_t)(b*80 + c)*HWSZ + y0*128 + p0;
        float2 t[6];
        t[0] = gt ? *(const float2*)(pl - 128) : make_float2(-1e30f, -1e30f);
        t[1] = *(const float2*)pl;
        t[2] = *(const float2*)(pl + 128);
        t[3] = *(const float2*)(pl + 256);
        t[4] = *(const float2*)(pl + 384);
        t[5] = gb ? *(const float2*)(pl + 512) : make_float2(-1e30f, -1e30f);
        #pragma unroll
        for (int i = 0; i < 4; i++) {
            float vm0 = fmaxf(t[i+1].x, fmaxf(t[i].x, t[i+2].x));
            float vm1 = fmaxf(t[i+1].y, fmaxf(t[i].y, t[i+2].y));
            float lft = __shfl_up(vm1, 1);   if (l == 0)  lft = -1e30f;
            float rgt = __shfl_down(vm0, 1); if (l == 63) rgt = -1e30f;
            float m0 = fmaxf(lft, fmaxf(vm0, vm1));
            float m1 = fmaxf(vm0, fmaxf(vm1, rgt));
            float k0 = (t[i+1].x == m0) ? t[i+1].x : 0.f;
            float k1 = (t[i+1].y == m1) ? t[i+1].y : 0.f;
            if (k0 > best[2*i])   { best[2*i]   = k0; bc[2*i]   = c; }
            if (k1 > best[2*i+1]) { best[2*i+1] = k1; bc[2*i+1] = c; }
        }
    }
    #pragma unroll
    for (int i = 0; i < 4; i++) {
        int o = b*HWSZ + (y0 + i)*128 + p0;
        *(float2*)&sc[o] = make_float2(best[2*i], best[2*i+1]);
        *(int2*)&cat[o]  = make_int2(bc[2*i], bc[2*i+1]);
    }
}

// ---------------------------------------------------------------------------
// Merge the 4 class-quarter partials into sc0/cat0 in place (strict > ->
// lowest class index wins ties == exact argmax).
// ---------------------------------------------------------------------------
__global__ __launch_bounds__(256) void k_merge4(float* __restrict__ sc0, int* __restrict__ cat0,
                                                const float* __restrict__ s1, const int* __restrict__ c1,
                                                const float* __restrict__ s2, const int* __restrict__ c2,
                                                const float* __restrict__ s3, const int* __restrict__ c3) {
    int i = (blockIdx.x * 256 + threadIdx.x) * 4;
    float4 a = *(const float4*)(sc0 + i);
    int4   ca = *(const int4*)(cat0 + i);
    {
        float4 bq = *(const float4*)(s1 + i);
        int4   cb = *(const int4*)(c1 + i);
        if (bq.x > a.x) { a.x = bq.x; ca.x = cb.x; }
        if (bq.y > a.y) { a.y = bq.y; ca.y = cb.y; }
        if (bq.z > a.z) { a.z = bq.z; ca.z = cb.z; }
        if (bq.w > a.w) { a.w = bq.w; ca.w = cb.w; }
    }
    {
        float4 bq = *(const float4*)(s2 + i);
        int4   cb = *(const int4*)(c2 + i);
        if (bq.x > a.x) { a.x = bq.x; ca.x = cb.x; }
        if (bq.y > a.y) { a.y = bq.y; ca.y = cb.y; }
        if (bq.z > a.z) { a.z = bq.z; ca.z = cb.z; }
        if (bq.w > a.w) { a.w = bq.w; ca.w = cb.w; }
    }
    {
        float4 bq = *(const float4*)(s3 + i);
        int4   cb = *(const int4*)(c3 + i);
        if (bq.x > a.x) { a.x = bq.x; ca.x = cb.x; }
        if (bq.y > a.y) { a.y = bq.y; ca.y = cb.y; }
        if (bq.z > a.z) { a.z = bq.z; ca.z = cb.z; }
        if (bq.w > a.w) { a.w = bq.w; ca.w = cb.w; }
    }
    *(float4*)(sc0 + i) = a;
    *(int4*)(cat0 + i)  = ca;
}

// ---------------------------------------------------------------------------
// k_select (verified r14): bisection top-100 + decode + NMS.
// ---------------------------------------------------------------------------
__global__ __launch_bounds__(256) void k_select(const float* __restrict__ sc,
                                                const int* __restrict__ cats,
                                                const float* __restrict__ regp,
                                                const float* __restrict__ whp,
                                                float* __restrict__ out) {
    const int b   = blockIdx.x;
    const int tid = threadIdx.x;
    const int wv  = tid >> 6, lane = tid & 63;
    const float* scb = sc + (size_t)b*HWSZ;

    __shared__ int   red[2][4];
    __shared__ uint  wtot[4];
    __shared__ int   gib[128];
    __shared__ uint  gvb[128];
    __shared__ int   ebuf[KK];
    __shared__ u64   keys[128];
    __shared__ int   s_inds[KK];
    __shared__ float s_vals[KK];
    __shared__ float X1[KK], Y1[KK], X2[KK], Y2[KK], AR[KK];

    f32x4 d[16];
    #pragma unroll
    for (int c = 0; c < 16; c++)
        d[c] = *(const f32x4*)(scb + c*1024 + tid*4);

    #define CNT_GT(T, OUTV) do {                                              \
        int myc_ = 0;                                                         \
        _Pragma("unroll")                                                     \
        for (int c = 0; c < 16; c++) {                                        \
            _Pragma("unroll")                                                 \
            for (int j = 0; j < 4; j++)                                       \
                myc_ += (__float_as_uint(d[c][j]) > (T)) ? 1 : 0;             \
        }                                                                     \
        _Pragma("unroll")                                                     \
        for (int o_ = 32; o_ >= 1; o_ >>= 1) myc_ += __shfl_xor(myc_, o_);    \
        if (lane == 0) red[par][wv] = myc_;                                   \
        __syncthreads();                                                      \
        OUTV = red[par][0] + red[par][1] + red[par][2] + red[par][3];         \
        par ^= 1;                                                             \
    } while (0)

    int par = 0;
    uint Vbits; uint G;
    {
        int tot0; CNT_GT(0u, tot0);
        if (tot0 < KK) { Vbits = 0u; G = (uint)tot0; }
        else {
            uint lo = 0u, hi = 0x7F800000u; int gHi = 0;
            while (hi - lo > 1u) {
                uint mid = lo + ((hi - lo) >> 1);
                int t_; CNT_GT(mid, t_);
                if (t_ >= KK) lo = mid; else { hi = mid; gHi = t_; }
            }
            Vbits = hi; G = (uint)gHi;
        }
    }
    #undef CNT_GT
    const uint Eneed = KK - G;

    f32x4 c4[16];
    #pragma unroll
    for (int c = 0; c < 16; c++)
        c4[c] = *(const f32x4*)(scb + tid*64 + c*4);

    uint cntG = 0, cntE = 0;
    #pragma unroll
    for (int c = 0; c < 16; c++)
        #pragma unroll
        for (int j = 0; j < 4; j++) {
            uint u = __float_as_uint(c4[c][j]);
            cntG += (u > Vbits) ? 1u : 0u;
            cntE += (u == Vbits) ? 1u : 0u;
        }
    uint pk = (cntE << 16) | cntG;
    uint v = pk;
    #pragma unroll
    for (int o = 1; o <= 32; o <<= 1) {
        uint ov = __shfl_up(v, o);
        if (lane >= o) v += ov;
    }
    if (lane == 63) wtot[wv] = v;
    __syncthreads();
    uint woff = 0;
    for (int i = 0; i < 4; i++) if (i < wv) woff += wtot[i];
    uint excl = v - pk + woff;
    uint pG = excl & 0xFFFFu, pE = excl >> 16;

    #pragma unroll
    for (int c = 0; c < 16; c++)
        #pragma unroll
        for (int j = 0; j < 4; j++) {
            uint u = __float_as_uint(c4[c][j]);
            int idx = tid*64 + c*4 + j;
            if (u > Vbits) { gib[pG] = idx; gvb[pG] = u; pG++; }
            else if (u == Vbits) { if (pE < Eneed) ebuf[pE] = idx; pE++; }
        }
    __syncthreads();

    if (tid < 128)
        keys[tid] = (tid < (int)G) ? (((u64)(~gvb[tid]) << 32) | (uint)gib[tid])
                                   : ~0ull;
    for (uint k2 = 2; k2 <= 128; k2 <<= 1) {
        for (uint j = k2 >> 1; j > 0; j >>= 1) {
            __syncthreads();
            if (tid < 128) {
                uint i = (uint)tid, ixj = i ^ j;
                if (ixj > i) {
                    u64 a = keys[i], bb = keys[ixj];
                    bool up = ((i & k2) == 0);
                    if ((a > bb) == up) { keys[i] = bb; keys[ixj] = a; }
                }
            }
        }
    }
    __syncthreads();

    if (tid < KK) {
        if (tid < (int)G) {
            u64 kk2 = keys[tid];
            s_inds[tid] = (int)(uint)kk2;
            s_vals[tid] = __uint_as_float(~(uint)(kk2 >> 32));
        } else {
            s_inds[tid] = ebuf[tid - (int)G];
            s_vals[tid] = __uint_as_float(Vbits);
        }
    }
    __syncthreads();

    if (tid < KK) {  // decode boxes
        int ind   = s_inds[tid];
        float scv = s_vals[tid];
        const float* rb = regp + (size_t)b*2*HWSZ;
        const float* wb = whp  + (size_t)b*2*HWSZ;
        float r0 = rb[ind], r1 = rb[HWSZ + ind];
        float w0 = wb[ind], w1 = wb[HWSZ + ind];
        float ctx = (float)(ind & 127) + r0;
        float cty = (float)(ind >> 7) + r1;
        float x1 = (ctx - w0*0.5f)*4.f, y1 = (cty - w1*0.5f)*4.f;
        float x2 = (ctx + w0*0.5f)*4.f, y2 = (cty + w1*0.5f)*4.f;
        size_t bo = ((size_t)b*KK + tid)*4;
        out[bo+0] = x1; out[bo+1] = y1; out[bo+2] = x2; out[bo+3] = y2;
        out[BN*KK*4 + b*KK + tid]         = (float)cats[(size_t)b*HWSZ + ind];
        out[BN*KK*4 + BN*KK + b*KK + tid] = scv;
        X1[tid] = x1; Y1[tid] = y1; X2[tid] = x2; Y2[tid] = y2;
        AR[tid] = (x2 - x1)*(y2 - y1);
    }
    __syncthreads();

    if (tid < 64) {  // NMS in wave 0
        const int l = tid;
        float x1a = X1[l], y1a = Y1[l], x2a = X2[l], y2a = Y2[l], ara = AR[l];
        int   ka  = (s_vals[l] > 0.2f) ? 1 : 0;
        float x1b = 0, y1b = 0, x2b = 0, y2b = 0, arb = 0;
        int   kb  = 0;
        if (l < KK - 64) {
            x1b = X1[64+l]; y1b = Y1[64+l]; x2b = X2[64+l]; y2b = Y2[64+l];
            arb = AR[64+l];
            kb  = (s_vals[64+l] > 0.2f) ? 1 : 0;
        }
        for (int i = 0; i < KK; i++) {
            float jx1, jy1, jx2, jy2, jar; int jk;
            if (i < 64) {
                jx1 = __shfl(x1a, i); jy1 = __shfl(y1a, i);
                jx2 = __shfl(x2a, i); jy2 = __shfl(y2a, i);
                jar = __shfl(ara, i); jk  = __shfl(ka,  i);
            } else {
                int li = i - 64;
                jx1 = __shfl(x1b, li); jy1 = __shfl(y1b, li);
                jx2 = __shfl(x2b, li); jy2 = __shfl(y2b, li);
                jar = __shfl(arb, li); jk  = __shfl(kb,  li);
            }
            if (jk) {
                if (ka && l > i) {
                    float iw = fminf(jx2, x2a) - fmaxf(jx1, x1a); iw = iw > 0.f ? iw : 0.f;
                    float ih = fminf(jy2, y2a) - fmaxf(jy1, y1a); ih = ih > 0.f ? ih : 0.f;
                    float inter = iw*ih;
                    float iou = inter / (jar + ara - inter + 1e-9f);
                    if (iou > 0.5f) ka = 0;
                }
                if (kb && (64 + l) > i) {
                    float iw = fminf(jx2, x2b) - fmaxf(jx1, x1b); iw = iw > 0.f ? iw : 0.f;
                    float ih = fminf(jy2, y2b) - fmaxf(jy1, y1b); ih = ih > 0.f ? ih : 0.f;
                    float inter = iw*ih;
                    float iou = inter / (jar + arb - inter + 1e-9f);
                    if (iou > 0.5f) kb = 0;
                }
            }
        }
        int koff = BN*KK*4 + 2*BN*KK;
        out[koff + b*KK + l] = ka ? 1.f : 0.f;
        if (l < KK - 64) out[koff + b*KK + 64 + l] = kb ? 1.f : 0.f;
    }
}

// ---------------------------------------------------------------------------
extern "C" void kernel_launch(void* const* d_in, const int* in_sizes, int n_in,
                              void* d_out, int out_size, void* d_ws, size_t ws_size,
                              hipStream_t stream) {
    const float* x      = (const float*)d_in[0];
    const float* cls_w1 = (const float*)d_in[1];
    const float* cls_b1 = (const float*)d_in[2];
    const float* cls_w2 = (const float*)d_in[3];
    const float* cls_b2 = (const float*)d_in[4];
    const float* reg_w1 = (const float*)d_in[5];
    const float* reg_b1 = (const float*)d_in[6];
    const float* reg_w2 = (const float*)d_in[7];
    const float* reg_b2 = (const float*)d_in[8];
    const float* wh_w1  = (const float*)d_in[9];
    const float* wh_b1  = (const float*)d_in[10];
    const float* wh_w2  = (const float*)d_in[11];
    const float* wh_b2  = (const float*)d_in[12];

    float* ws   = (float*)d_ws;
    float* clsb = ws + WS_CLS;
    float* regb = ws + WS_REG;
    float* whb  = ws + WS_WH;
    float* scw  = ws + WS_SC;
    int*   cat  = (int*)(ws + WS_CAT);
    f16*   w1h  = (f16*)(ws + WS_W1H);
    f16*   w1l  = (f16*)(ws + WS_W1L);
    f16*   w2h  = (f16*)(ws + WS_W2H);
    f16*   w2l  = (f16*)(ws + WS_W2L);
    f16*   xth  = (f16*)(ws + WS_XTH);
    f16*   xtl  = (f16*)(ws + WS_XTL);
    f16*   zr   = (f16*)(ws + WS_ZR);
    float* sc1  = ws + WS_SC1;
    int*   cat1 = (int*)(ws + WS_CAT1);
    float* sc2  = ws + WS_SC2;
    int*   cat2 = (int*)(ws + WS_CAT2);
    float* sc3  = ws + WS_SC3;
    int*   cat3 = (int*)(ws + WS_CAT3);
    float* out  = (float*)d_out;

    const bool big = ws_size >= (size_t)WS_END4 * 4u;

    k_prep<<<(3*9*64*64 + 112*64 + 255)/256, 256, 0, stream>>>(
        cls_w1, reg_w1, wh_w1, cls_w2, reg_w2, wh_w2, w1h, w1l, w2h, w2l,
        big ? (float*)(ws + WS_ZR) : (float*)0);
    if (big) {
        k_prepx<<<NREG, 256, 0, stream>>>(x, xth, xtl);
        k_conv_rw<<<dim3(2, 64, 16), 256, 0, stream>>>(
            xth, xtl, zr, w1h, w1l, w2h, w2l, reg_b1, wh_b1,
            reg_b2, wh_b2, regb, whb);
        k_conv_c<<<dim3(2, 64, 16), 256, 0, stream>>>(
            xth, xtl, zr, w1h, w1l, w2h, w2l, cls_b1, cls_b2, clsb);
        k_peaks<<<dim3(8, 16, 4), 256, 0, stream>>>(
            clsb, scw, cat, sc1, cat1, sc2, cat2, sc3, cat3, 20);
        k_merge4<<<256, 256, 0, stream>>>(scw, cat, sc1, cat1, sc2, cat2, sc3, cat3);
    } else {
        k_conv_fb<<<dim3(2, 128, 16), 256, 0, stream>>>(
            x, w1h, w1l, w2h, w2l, cls_b1, reg_b1, wh_b1,
            cls_b2, reg_b2, wh_b2, clsb, regb, whb);
        k_peaks<<<dim3(8, 16, 1), 256, 0, stream>>>(
            clsb, scw, cat, scw, cat, scw, cat, scw, cat, 80);
    }
    k_select<<<16, 256, 0, stream>>>(scw, cat, regb, whb, out);
}

// Round 11
// 441.848 us; speedup vs baseline: 1.2867x; 1.2867x over previous
//
#include <hip/hip_runtime.h>
#include <math.h>

// Problem constants
#define BN 16
#define HWSZ 16384
#define NC 80
#define KK 100

typedef _Float16 f16;
typedef _Float16 f16x2 __attribute__((ext_vector_type(2)));
typedef _Float16 f16x4 __attribute__((ext_vector_type(4)));
typedef _Float16 f16x8 __attribute__((ext_vector_type(8)));
typedef float    f32x4 __attribute__((ext_vector_type(4)));
typedef unsigned int uint;
typedef unsigned long long u64;

// ---- workspace layout (float units) ----
#define WS_CLS   0
#define CLS_SZ   (BN*NC*HWSZ)
#define WS_REG   (WS_CLS + CLS_SZ)
#define REG_SZ   (BN*2*HWSZ)
#define WS_WH    (WS_REG + REG_SZ)
#define WH_SZ    (BN*2*HWSZ)
#define WS_SC    (WS_WH + WH_SZ)
#define SC_SZ    (BN*HWSZ)
#define WS_CAT   (WS_SC + SC_SZ)
#define CAT_SZ   (BN*HWSZ)
#define WS_W1H   (WS_CAT + CAT_SZ)             // f16 3*9*64*64 -> 55296 floats/plane
#define W1F      (110592/2)
#define WS_W1L   (WS_W1H + W1F)
#define WS_W2H   (WS_W1L + W1F)                // f16 112*64 (padded) -> 3584 floats/plane
#define W2F      (7168/2)
#define WS_W2L   (WS_W2H + W2F)
// Pre-split/pre-transposed x in (swizzled) LDS-image layout.
// Region = (b,gy,h,chunk): 66 rows x 32ci f16 = 2112 f16 = 4224 B.
#define NREG     (BN*128*2*2)                  // 8192 regions
#define WS_XTH   (WS_W2L + W2F)
#define XT_F     (NREG*2112/2)
#define WS_XTL   (WS_XTH + XT_F)
#define WS_ZR    (WS_XTL + XT_F)               // 4224 B zero region (f16)
#define ZR_F     1056
// partial peak buffers for class-split k_peaks (quarters 1..3)
#define WS_SC1   (WS_ZR + ZR_F)
#define WS_CAT1  (WS_SC1 + SC_SZ)
#define WS_SC2   (WS_CAT1 + CAT_SZ)
#define WS_CAT2  (WS_SC2 + SC_SZ)
#define WS_SC3   (WS_CAT2 + CAT_SZ)
#define WS_CAT3  (WS_SC3 + SC_SZ)
#define WS_END4  (WS_CAT3 + CAT_SZ)

// scaling: x*16, w*256 -> acc = 4096*true
#define SCL_X   16.0f
#define SCL_W   256.0f
#define INV_ACC (1.0f/4096.0f)

// async global->LDS, 16B per lane (dest = wave-uniform base + lane*16)
#define GL2LDS(g, l) __builtin_amdgcn_global_load_lds( \
    (__attribute__((address_space(1))) unsigned int*)(unsigned long long)(const void*)(g), \
    (__attribute__((address_space(3))) unsigned int*)(unsigned int)(unsigned long long)(void*)(l), \
    16, 0, 0)

// ---------------------------------------------------------------------------
// Prep: split weights to fp16 hi/lo (scaled by 256); zero the zero-region.
// ---------------------------------------------------------------------------
__global__ void k_prep(const float* __restrict__ cw1, const float* __restrict__ rw1,
                       const float* __restrict__ ww1, const float* __restrict__ cw2,
                       const float* __restrict__ rw2, const float* __restrict__ ww2,
                       f16* __restrict__ w1h, f16* __restrict__ w1l,
                       f16* __restrict__ w2h, f16* __restrict__ w2l,
                       float* __restrict__ zr) {
    int idx = blockIdx.x * 256 + threadIdx.x;
    if (idx < 3*9*64*64) {
        int ci = idx & 63, co = (idx >> 6) & 63;
        int s  = (idx >> 12) % 9, br = idx / 36864;
        const float* src = (br == 0) ? cw1 : (br == 1 ? rw1 : ww1);
        float v = src[(co*64 + ci)*9 + s] * SCL_W;
        f16 h = (f16)v;
        w1h[idx] = h; w1l[idx] = (f16)(v - (float)h);
    }
    int j = idx - 3*9*64*64;
    if (j >= 0 && j < 112*64) {
        int ci = j & 63, row = j >> 6;
        float v = 0.f;
        if (row < 80)                    v = cw2[row*64 + ci];
        else if (row < 82)               v = rw2[(row-80)*64 + ci];
        else if (row >= 96 && row < 98)  v = ww2[(row-96)*64 + ci];
        v *= SCL_W;
        f16 h = (f16)v;
        w2h[j] = h; w2l[j] = (f16)(v - (float)h);
    }
    if (zr && idx < ZR_F) zr[idx] = 0.f;
}

// ---------------------------------------------------------------------------
// Pre-split + pre-transpose x into per-(b,gy,h,chunk) regions, with the 16B
// slot swizzle baked into the GLOBAL layout (gl2lds writes linearly, so the
// source permutation IS the LDS permutation).
// ---------------------------------------------------------------------------
__global__ __launch_bounds__(256) void k_prepx(const float* __restrict__ x,
                                               f16* __restrict__ xth,
                                               f16* __restrict__ xtl) {
    const int reg = blockIdx.x;
    const int chunk = reg & 1, hh = (reg >> 1) & 1;
    const int gy = (reg >> 2) & 127, b = reg >> 9;
    __shared__ f16 th[66*72] __attribute__((aligned(16)));
    __shared__ f16 tl[66*72] __attribute__((aligned(16)));
    const int tid = threadIdx.x;
    const float* xb = x + ((size_t)(b*64 + chunk*32))*HWSZ + gy*128;
    #pragma unroll
    for (int it = 0; it < 9; it++) {
        int idx = it*256 + tid;
        if (idx < 2112) {
            int ci = idx / 66, pxi = idx - ci*66;
            int gp = hh*64 - 1 + pxi;
            float v = 0.f;
            if (gp >= 0 && gp < 128) v = xb[(size_t)ci*HWSZ + gp] * SCL_X;
            f16 hv = (f16)v;
            th[pxi*72 + ci] = hv;
            tl[pxi*72 + ci] = (f16)(v - (float)hv);
        }
    }
    __syncthreads();
    f16* oh = xth + (size_t)reg*2112;
    f16* ol = xtl + (size_t)reg*2112;
    {
        int row = tid >> 2, q = tid & 3;
        int sq = q ^ ((row >> 1) & 3);
        *(f16x8*)(oh + row*32 + sq*8) = *(const f16x8*)(th + row*72 + q*8);
        *(f16x8*)(ol + row*32 + sq*8) = *(const f16x8*)(tl + row*72 + q*8);
        if (tid < 8) {
            int u2 = 256 + tid, row2 = u2 >> 2, q2 = u2 & 3;
            int sq2 = q2 ^ ((row2 >> 1) & 3);
            *(f16x8*)(oh + row2*32 + sq2*8) = *(const f16x8*)(th + row2*72 + q2*8);
            *(f16x8*)(ol + row2*32 + sq2*8) = *(const f16x8*)(tl + row2*72 + q2*8);
        }
    }
}

// ---------------------------------------------------------------------------
// Fused MFMA conv — r17 configuration, the verified optimum of this family
// (r14 B-dbuf, r18 (256,3), r19 depth-1 prefetch, r20 branch-split all
// spilled and regressed; ledger: the 96-AGPR acc + epilogue needs the full
// 2-wave/SIMD 224-reg operating point).  2-row blocking, 72 MFMAs per 6
// B-loads, A-frag lifetime split, XOR-swizzled A reads, async STAGE4.
// ---------------------------------------------------------------------------
#define ABUF 8448                    // bytes per A buffer (hi 4224 + lo 4224)
__global__ __launch_bounds__(256, 2) void k_conv(
    const f16* __restrict__ xth, const f16* __restrict__ xtl, const f16* __restrict__ zreg,
    const f16* __restrict__ w1h, const f16* __restrict__ w1l,
    const f16* __restrict__ w2h, const f16* __restrict__ w2l,
    const float* __restrict__ b1c, const float* __restrict__ b1r, const float* __restrict__ b1w,
    const float* __restrict__ b2c, const float* __restrict__ b2r, const float* __restrict__ b2w,
    float* __restrict__ cls_o, float* __restrict__ reg_o, float* __restrict__ wh_o)
{
    __shared__ char smem[4*ABUF] __attribute__((aligned(16)));   // 33792 B
    f16* Rh = (f16*)smem;                 // epilogue alias over A buffers
    f16* Rl = (f16*)(smem + 9216);

    // XCD-aware bijective swizzle (2048 % 8 == 0).
    const int p  = blockIdx.x + 2*blockIdx.y + 128*blockIdx.z;
    const int lg = (p & 7)*256 + (p >> 3);
    const int b  = lg >> 7;
    const int y0 = ((lg & 127) >> 1) * 2;      // rows y0, y0+1
    const int h  = lg & 1;

    const int tid = threadIdx.x;
    const int w = tid >> 6, lane = tid & 63;
    const int l15 = lane & 15, quad = lane >> 4;
    const int co = w*16 + l15;

    // stage 4 regions (gy = y0-1 .. y0+2) of chunk ch into buffers 0..3
    #define STAGE4(ch) do {                                                   \
        _Pragma("unroll")                                                     \
        for (int gyi = 0; gyi < 4; gyi++) {                                   \
            const int gy_ = y0 - 1 + gyi;                                     \
            const f16* sh_; const f16* sl_;                                   \
            if (gy_ >= 0 && gy_ < 128) {                                      \
                size_t ro_ = (size_t)(((b*128 + gy_)*2 + h)*2 + (ch)) * 2112; \
                sh_ = xth + ro_; sl_ = xtl + ro_;                             \
            } else { sh_ = zreg; sl_ = zreg; }                                \
            char* db_ = smem + gyi*ABUF;                                      \
            GL2LDS(sh_ + tid*8, db_ + tid*16);                                \
            GL2LDS(sl_ + tid*8, db_ + 4224 + tid*16);                         \
            if (tid < 8) {                                                    \
                GL2LDS(sh_ + 2048 + tid*8, db_ + 4096 + tid*16);              \
                GL2LDS(sl_ + 2048 + tid*8, db_ + 4224 + 4096 + tid*16);       \
            }                                                                 \
        }                                                                     \
    } while (0)

    f32x4 accA[3][4], accB[3][4];
    #pragma unroll
    for (int br = 0; br < 3; br++)
        #pragma unroll
        for (int m = 0; m < 4; m++) {
            accA[br][m] = (f32x4){0.f,0.f,0.f,0.f};
            accB[br][m] = (f32x4){0.f,0.f,0.f,0.f};
        }

    // phase ph = chunk: row0 (y0) uses A-region gyi=r; row1 (y0+1) uses gyi=r+1.
    // B fragment identical for both rows -> 72 MFMAs per 6 B loads.
    #define COMPUTE(ph) do {                                                  \
        for (int r = 0; r < 3; r++) {                                         \
            const f16* A0 = (const f16*)(smem + r*ABUF);                      \
            const f16* A1 = (const f16*)(smem + (r+1)*ABUF);                  \
            _Pragma("unroll")                                                 \
            for (int dx = 0; dx < 3; dx++) {                                  \
                const int s = r*3 + dx;                                       \
                f16x8 bh[3], bl[3];                                           \
                _Pragma("unroll")                                             \
                for (int br = 0; br < 3; br++) {                              \
                    size_t k = ((size_t)((br*9 + s)*64 + co))*64 + (ph)*32 + quad*8; \
                    bh[br] = *(const f16x8*)(w1h + k);                        \
                    bl[br] = *(const f16x8*)(w1l + k);                        \
                }                                                             \
                _Pragma("unroll")                                             \
                for (int m = 0; m < 4; m++) {                                 \
                    const int row = m*16 + l15 + dx;                          \
                    const int off = row*32 + ((quad ^ ((row >> 1) & 3)) << 3);\
                    {                                                         \
                        f16x8 ah0 = *(const f16x8*)(A0 + off);                \
                        f16x8 al0 = *(const f16x8*)(A0 + 2112 + off);         \
                        _Pragma("unroll")                                     \
                        for (int br = 0; br < 3; br++) {                      \
                            accA[br][m] = __builtin_amdgcn_mfma_f32_16x16x32_f16(ah0, bh[br], accA[br][m], 0,0,0); \
                            accA[br][m] = __builtin_amdgcn_mfma_f32_16x16x32_f16(ah0, bl[br], accA[br][m], 0,0,0); \
                            accA[br][m] = __builtin_amdgcn_mfma_f32_16x16x32_f16(al0, bh[br], accA[br][m], 0,0,0); \
                        }                                                     \
                    }                                                         \
                    {                                                         \
                        f16x8 ah1 = *(const f16x8*)(A1 + off);                \
                        f16x8 al1 = *(const f16x8*)(A1 + 2112 + off);         \
                        _Pragma("unroll")                                     \
                        for (int br = 0; br < 3; br++) {                      \
                            accB[br][m] = __builtin_amdgcn_mfma_f32_16x16x32_f16(ah1, bh[br], accB[br][m], 0,0,0); \
                            accB[br][m] = __builtin_amdgcn_mfma_f32_16x16x32_f16(ah1, bl[br], accB[br][m], 0,0,0); \
                            accB[br][m] = __builtin_amdgcn_mfma_f32_16x16x32_f16(al1, bh[br], accB[br][m], 0,0,0); \
                        }                                                     \
                    }                                                         \
                }                                                             \
            }                                                                 \
        }                                                                     \
    } while (0)

    STAGE4(0);
    __syncthreads();        // chunk 0 resident
    COMPUTE(0);
    __syncthreads();        // all reads of chunk-0 buffers done
    STAGE4(1);
    __syncthreads();        // chunk 1 resident
    COMPUTE(1);

    #undef STAGE4
    #undef COMPUTE

    // ======================= epilogue: per branch x per row =======================
    #define EPIROW(ACC, yy) do {                                              \
        __syncthreads();              /* prior A/conv2 reads done */          \
        _Pragma("unroll")                                                     \
        for (int m = 0; m < 4; m++)                                           \
            _Pragma("unroll")                                                 \
            for (int rg = 0; rg < 4; rg++) {                                  \
                float t = fmaxf(ACC[br][m][rg]*INV_ACC + b1v, 0.f) * SCL_X;   \
                f16 hh = (f16)t;                                              \
                int pxl = m*16 + quad*4 + rg;                                 \
                Rh[pxl*72 + co] = hh;                                         \
                Rl[pxl*72 + co] = (f16)(t - (float)hh);                       \
            }                                                                 \
        __syncthreads();                                                      \
        const int NT     = (br == 0) ? 5 : 1;                                 \
        const int rowoff = (br == 0) ? 0 : (br == 1 ? 80 : 96);               \
        f32x4 a2[5];                                                          \
        _Pragma("unroll")                                                     \
        for (int n = 0; n < 5; n++) a2[n] = (f32x4){0.f,0.f,0.f,0.f};         \
        _Pragma("unroll")                                                     \
        for (int kc = 0; kc < 64; kc += 32) {                                 \
            int off = co*72 + kc + quad*8;                                    \
            f16x8 xh = *(const f16x8*)(Rh + off);                             \
            f16x8 xl = *(const f16x8*)(Rl + off);                             \
            _Pragma("unroll")                                                 \
            for (int n = 0; n < 5; n++) {                                     \
                if (n >= NT) break;                                           \
                const f16* g2h = w2h + (rowoff + n*16 + l15)*64 + kc + quad*8;\
                const f16* g2l = w2l + (rowoff + n*16 + l15)*64 + kc + quad*8;\
                f16x8 bh2 = *(const f16x8*)g2h;                               \
                f16x8 bl2 = *(const f16x8*)g2l;                               \
                a2[n] = __builtin_amdgcn_mfma_f32_16x16x32_f16(xh, bh2, a2[n], 0,0,0); \
                a2[n] = __builtin_amdgcn_mfma_f32_16x16x32_f16(xh, bl2, a2[n], 0,0,0); \
                a2[n] = __builtin_amdgcn_mfma_f32_16x16x32_f16(xl, bh2, a2[n], 0,0,0); \
            }                                                                 \
        }                                                                     \
        const int pxg = h*64 + w*16 + quad*4;                                 \
        if (br == 0) {                                                        \
            _Pragma("unroll")                                                 \
            for (int n = 0; n < 5; n++) {                                     \
                int co2 = n*16 + l15;                                         \
                float bb = b2c[co2];                                          \
                _Pragma("unroll")                                             \
                for (int rg = 0; rg < 4; rg++) {                              \
                    float sv = a2[n][rg]*INV_ACC + bb;                        \
                    cls_o[((size_t)(b*80 + co2)*128 + (yy))*128 + pxg + rg] = 1.f/(1.f + expf(-sv)); \
                }                                                             \
            }                                                                 \
        } else {                                                              \
            if (l15 < 2) {                                                    \
                const float* b2 = (br == 1) ? b2r : b2w;                      \
                float* outp     = (br == 1) ? reg_o : wh_o;                   \
                float bb = b2[l15];                                           \
                _Pragma("unroll")                                             \
                for (int rg = 0; rg < 4; rg++) {                              \
                    float sv = a2[0][rg]*INV_ACC + bb;                        \
                    float o  = (br == 1) ? (1.f/(1.f + expf(-sv))) : expf(sv);\
                    outp[((size_t)(b*2 + l15))*HWSZ + (yy)*128 + pxg + rg] = o; \
                }                                                             \
            }                                                                 \
        }                                                                     \
    } while (0)

    #pragma unroll
    for (int br = 0; br < 3; br++) {
        const float* b1 = (br == 0) ? b1c : (br == 1 ? b1r : b1w);
        const float b1v = b1[co];
        EPIROW(accA, y0);
        EPIROW(accB, y0 + 1);
    }
    #undef EPIROW
}

// ---------------------------------------------------------------------------
// Fallback conv (r11 kernel) — used only if ws_size can't hold the pre-split
// x planes.  Bit-identical outputs to k_conv.
// ---------------------------------------------------------------------------
#define A_STRIDE 36
#define ABUF_FB  9504
__global__ __launch_bounds__(256) void k_conv_fb(
    const float* __restrict__ x,
    const f16* __restrict__ w1h, const f16* __restrict__ w1l,
    const f16* __restrict__ w2h, const f16* __restrict__ w2l,
    const float* __restrict__ b1c, const float* __restrict__ b1r, const float* __restrict__ b1w,
    const float* __restrict__ b2c, const float* __restrict__ b2r, const float* __restrict__ b2w,
    float* __restrict__ cls_o, float* __restrict__ reg_o, float* __restrict__ wh_o)
{
    __shared__ char smem[19008] __attribute__((aligned(16)));
    f16* Rh = (f16*)smem;
    f16* Rl = (f16*)(smem + 9216);

    const int h = blockIdx.x, y = blockIdx.y, b = blockIdx.z;
    const int tid = threadIdx.x;
    const int w = tid >> 6, lane = tid & 63;
    const int l15 = lane & 15, quad = lane >> 4;

    static const int CS[6] = {0,0,0,1,1,1};
    static const int RS[6] = {0,1,2,0,1,2};

    #define STAGEF(bufi, si_) do {                                            \
        const int gy = y - 1 + RS[si_];                                       \
        const bool ok = (gy >= 0) && (gy < 128);                              \
        const float* xp = x + ((size_t)(b*64 + CS[si_]*32)*128 + gy)*128;     \
        f16x2* dh = (f16x2*)(smem + (bufi)*ABUF_FB);                          \
        f16x2* dl = (f16x2*)(smem + (bufi)*ABUF_FB + 4752);                   \
        _Pragma("unroll")                                                     \
        for (int e0 = 0; e0 < 1024; e0 += 256) {                              \
            int e = e0 + tid;                                                 \
            int pxl = e & 63, cp = e >> 6;                                    \
            float v0 = 0.f, v1 = 0.f;                                         \
            if (ok) { int g = h*64 + pxl;                                     \
                      v0 = xp[(size_t)(2*cp)*HWSZ + g]*SCL_X;                 \
                      v1 = xp[(size_t)(2*cp+1)*HWSZ + g]*SCL_X; }             \
            f16 h0 = (f16)v0, h1 = (f16)v1;                                   \
            f16 l0 = (f16)(v0 - (float)h0), l1 = (f16)(v1 - (float)h1);       \
            int wi = (pxl + 1)*18 + cp;                                       \
            dh[wi] = (f16x2){h0, h1};                                         \
            dl[wi] = (f16x2){l0, l1};                                         \
        }                                                                     \
        if (tid < 32) {                                                       \
            int side = tid >> 4, cp = tid & 15;                               \
            bool valid = ok && (side ? (h == 0) : (h == 1));                  \
            int g = side ? 64 : 63;                                           \
            float v0 = 0.f, v1 = 0.f;                                         \
            if (valid) { v0 = xp[(size_t)(2*cp)*HWSZ + g]*SCL_X;              \
                         v1 = xp[(size_t)(2*cp+1)*HWSZ + g]*SCL_X; }          \
            f16 h0 = (f16)v0, h1 = (f16)v1;                                   \
            f16 l0 = (f16)(v0 - (float)h0), l1 = (f16)(v1 - (float)h1);       \
            int wi = (side ? 65 : 0)*18 + cp;                                 \
            dh[wi] = (f16x2){h0, h1};                                         \
            dl[wi] = (f16x2){l0, l1};                                         \
        }                                                                     \
    } while (0)

    f32x4 acc[3][4];
    #pragma unroll
    for (int br = 0; br < 3; br++)
        #pragma unroll
        for (int m = 0; m < 4; m++) acc[br][m] = (f32x4){0.f,0.f,0.f,0.f};

    STAGEF(0, 0);
    __syncthreads();

    for (int si = 0; si < 6; si++) {
        const int cur = si & 1;
        if (si < 5) STAGEF(cur ^ 1, si + 1);
        const f16* APh = (const f16*)(smem + cur*ABUF_FB);
        const f16* APl = APh + 2376;
        const int chunk = CS[si], r = RS[si];
        #pragma unroll
        for (int dx = 0; dx < 3; dx++) {
            const int s = r*3 + dx;
            f16x8 bh[3], bl[3];
            #pragma unroll
            for (int br = 0; br < 3; br++) {
                size_t k = ((size_t)((br*9 + s)*64 + (w*16 + l15)))*64 + chunk*32 + quad*8;
                bh[br] = *(const f16x8*)(w1h + k);
                bl[br] = *(const f16x8*)(w1l + k);
            }
            #pragma unroll
            for (int m = 0; m < 4; m++) {
                int off = (m*16 + l15 + dx)*A_STRIDE + quad*8;
                f16x4 h0 = *(const f16x4*)(APh + off);
                f16x4 h1 = *(const f16x4*)(APh + off + 4);
                f16x4 u0 = *(const f16x4*)(APl + off);
                f16x4 u1 = *(const f16x4*)(APl + off + 4);
                f16x8 ah = __builtin_shufflevector(h0, h1, 0,1,2,3,4,5,6,7);
                f16x8 al = __builtin_shufflevector(u0, u1, 0,1,2,3,4,5,6,7);
                #pragma unroll
                for (int br = 0; br < 3; br++) {
                    acc[br][m] = __builtin_amdgcn_mfma_f32_16x16x32_f16(ah, bh[br], acc[br][m], 0,0,0);
                    acc[br][m] = __builtin_amdgcn_mfma_f32_16x16x32_f16(ah, bl[br], acc[br][m], 0,0,0);
                    acc[br][m] = __builtin_amdgcn_mfma_f32_16x16x32_f16(al, bh[br], acc[br][m], 0,0,0);
                }
            }
        }
        __syncthreads();
    }
    #undef STAGEF

    #pragma unroll
    for (int br = 0; br < 3; br++) {
        const float* b1 = (br == 0) ? b1c : (br == 1 ? b1r : b1w);
        const float b1v = b1[w*16 + l15];
        __syncthreads();
        #pragma unroll
        for (int m = 0; m < 4; m++)
            #pragma unroll
            for (int rg = 0; rg < 4; rg++) {
                float t = fmaxf(acc[br][m][rg]*INV_ACC + b1v, 0.f) * SCL_X;
                f16 hh = (f16)t;
                int pxl = m*16 + quad*4 + rg;
                int co  = w*16 + l15;
                Rh[pxl*72 + co] = hh;
                Rl[pxl*72 + co] = (f16)(t - (float)hh);
            }
        __syncthreads();

        const int NT     = (br == 0) ? 5 : 1;
        const int rowoff = (br == 0) ? 0 : (br == 1 ? 80 : 96);
        f32x4 a2[5];
        #pragma unroll
        for (int n = 0; n < 5; n++) a2[n] = (f32x4){0.f,0.f,0.f,0.f};

        #pragma unroll
        for (int kc = 0; kc < 64; kc += 32) {
            int off = (w*16 + l15)*72 + kc + quad*8;
            f16x8 xh = *(const f16x8*)(Rh + off);
            f16x8 xl = *(const f16x8*)(Rl + off);
            #pragma unroll
            for (int n = 0; n < 5; n++) {
                if (n >= NT) break;
                const f16* g2h = w2h + (rowoff + n*16 + l15)*64 + kc + quad*8;
                const f16* g2l = w2l + (rowoff + n*16 + l15)*64 + kc + quad*8;
                f16x8 bh = *(const f16x8*)g2h;
                f16x8 bl = *(const f16x8*)g2l;
                a2[n] = __builtin_amdgcn_mfma_f32_16x16x32_f16(xh, bh, a2[n], 0,0,0);
                a2[n] = __builtin_amdgcn_mfma_f32_16x16x32_f16(xh, bl, a2[n], 0,0,0);
                a2[n] = __builtin_amdgcn_mfma_f32_16x16x32_f16(xl, bh, a2[n], 0,0,0);
            }
        }

        const int pxg = h*64 + w*16 + quad*4;
        if (br == 0) {
            #pragma unroll
            for (int n = 0; n < 5; n++) {
                int co2 = n*16 + l15;
                float bb = b2c[co2];
                #pragma unroll
                for (int rg = 0; rg < 4; rg++) {
                    float sv = a2[n][rg]*INV_ACC + bb;
                    cls_o[((size_t)(b*80 + co2)*128 + y)*128 + pxg + rg] = 1.f/(1.f + expf(-sv));
                }
            }
        } else {
            if (l15 < 2) {
                const float* b2 = (br == 1) ? b2r : b2w;
                float* outp     = (br == 1) ? reg_o : wh_o;
                float bb = b2[l15];
                #pragma unroll
                for (int rg = 0; rg < 4; rg++) {
                    float sv = a2[0][rg]*INV_ACC + bb;
                    float o  = (br == 1) ? (1.f/(1.f + expf(-sv))) : expf(sv);
                    outp[((size_t)(b*2 + l15))*HWSZ + y*128 + pxg + rg] = o;
                }
            }
        }
    }
}

// ---------------------------------------------------------------------------
// 3x3 peak mask + max/argmax over a CLASS RANGE (4 rows per wave, verified
// r17).  blockIdx.z = class quarter (span 20); fallback: span 80, z=1.
// ---------------------------------------------------------------------------
__global__ __launch_bounds__(256) void k_peaks(const float* __restrict__ cls,
                                               float* __restrict__ scA, int* __restrict__ catA,
                                               float* __restrict__ scB, int* __restrict__ catB,
                                               float* __restrict__ scC, int* __restrict__ catC,
                                               float* __restrict__ scD, int* __restrict__ catD,
                                               int span) {
    const int b  = blockIdx.y;
    const int z  = blockIdx.z;
    const int c0 = z * span, c1 = c0 + span;
    float* __restrict__ sc  = (z == 0) ? scA  : (z == 1) ? scB  : (z == 2) ? scC  : scD;
    int*   __restrict__ cat = (z == 0) ? catA : (z == 1) ? catB : (z == 2) ? catC : catD;
    const int wv = threadIdx.x >> 6;
    const int l  = threadIdx.x & 63;
    const int y0 = blockIdx.x * 16 + wv * 4;    // rows y0 .. y0+3
    const int p0 = l * 2;
    const bool gt = (y0 > 0);
    const bool gb = (y0 + 4 < 128);
    float best[8]; int bc[8];
    #pragma unroll
    for (int i = 0; i < 8; i++) { best[i] = -1.f; bc[i] = c0; }
    for (int c = c0; c < c1; c++) {
        const float* pl = cls + (size_t)(b*80 + c)*HWSZ + y0*128 + p0;
        float2 t[6];
        t[0] = gt ? *(const float2*)(pl - 128) : make_float2(-1e30f, -1e30f);
        t[1] = *(const float2*)pl;
        t[2] = *(const float2*)(pl + 128);
        t[3] = *(const float2*)(pl + 256);
        t[4] = *(const float2*)(pl + 384);
        t[5] = gb ? *(const float2*)(pl + 512) : make_float2(-1e30f, -1e30f);
        #pragma unroll
        for (int i = 0; i < 4; i++) {
            // row y0+i: cur=t[i+1], tp=t[i], bt=t[i+2] — same fmax order
            float vm0 = fmaxf(t[i+1].x, fmaxf(t[i].x, t[i+2].x));
            float vm1 = fmaxf(t[i+1].y, fmaxf(t[i].y, t[i+2].y));
            float lft = __shfl_up(vm1, 1);   if (l == 0)  lft = -1e30f;
            float rgt = __shfl_down(vm0, 1); if (l == 63) rgt = -1e30f;
            float m0 = fmaxf(lft, fmaxf(vm0, vm1));
            float m1 = fmaxf(vm0, fmaxf(vm1, rgt));
            float k0 = (t[i+1].x == m0) ? t[i+1].x : 0.f;
            float k1 = (t[i+1].y == m1) ? t[i+1].y : 0.f;
            if (k0 > best[2*i])   { best[2*i]   = k0; bc[2*i]   = c; }
            if (k1 > best[2*i+1]) { best[2*i+1] = k1; bc[2*i+1] = c; }
        }
    }
    #pragma unroll
    for (int i = 0; i < 4; i++) {
        int o = b*HWSZ + (y0 + i)*128 + p0;
        *(float2*)&sc[o] = make_float2(best[2*i], best[2*i+1]);
        *(int2*)&cat[o]  = make_int2(bc[2*i], bc[2*i+1]);
    }
}

// ---------------------------------------------------------------------------
// Merge the 4 class-quarter partials into sc0/cat0 in place (strict > ->
// lowest class index wins ties == exact argmax).
// ---------------------------------------------------------------------------
__global__ __launch_bounds__(256) void k_merge4(float* __restrict__ sc0, int* __restrict__ cat0,
                                                const float* __restrict__ s1, const int* __restrict__ c1,
                                                const float* __restrict__ s2, const int* __restrict__ c2,
                                                const float* __restrict__ s3, const int* __restrict__ c3) {
    int i = (blockIdx.x * 256 + threadIdx.x) * 4;
    float4 a = *(const float4*)(sc0 + i);
    int4   ca = *(const int4*)(cat0 + i);
    {
        float4 bq = *(const float4*)(s1 + i);
        int4   cb = *(const int4*)(c1 + i);
        if (bq.x > a.x) { a.x = bq.x; ca.x = cb.x; }
        if (bq.y > a.y) { a.y = bq.y; ca.y = cb.y; }
        if (bq.z > a.z) { a.z = bq.z; ca.z = cb.z; }
        if (bq.w > a.w) { a.w = bq.w; ca.w = cb.w; }
    }
    {
        float4 bq = *(const float4*)(s2 + i);
        int4   cb = *(const int4*)(c2 + i);
        if (bq.x > a.x) { a.x = bq.x; ca.x = cb.x; }
        if (bq.y > a.y) { a.y = bq.y; ca.y = cb.y; }
        if (bq.z > a.z) { a.z = bq.z; ca.z = cb.z; }
        if (bq.w > a.w) { a.w = bq.w; ca.w = cb.w; }
    }
    {
        float4 bq = *(const float4*)(s3 + i);
        int4   cb = *(const int4*)(c3 + i);
        if (bq.x > a.x) { a.x = bq.x; ca.x = cb.x; }
        if (bq.y > a.y) { a.y = bq.y; ca.y = cb.y; }
        if (bq.z > a.z) { a.z = bq.z; ca.z = cb.z; }
        if (bq.w > a.w) { a.w = bq.w; ca.w = cb.w; }
    }
    *(float4*)(sc0 + i) = a;
    *(int4*)(cat0 + i)  = ca;
}

// ---------------------------------------------------------------------------
// k_select (verified r14): top-100 via integer bisection on float bits,
// deterministic index-ordered collect, 128-wide bitonic sort on
// (~valbits, idx) == (value desc, index asc) — exactly lax.top_k's order.
// Then box decode + NMS.
// ---------------------------------------------------------------------------
__global__ __launch_bounds__(256) void k_select(const float* __restrict__ sc,
                                                const int* __restrict__ cats,
                                                const float* __restrict__ regp,
                                                const float* __restrict__ whp,
                                                float* __restrict__ out) {
    const int b   = blockIdx.x;
    const int tid = threadIdx.x;
    const int wv  = tid >> 6, lane = tid & 63;
    const float* scb = sc + (size_t)b*HWSZ;

    __shared__ int   red[2][4];
    __shared__ uint  wtot[4];
    __shared__ int   gib[128];
    __shared__ uint  gvb[128];
    __shared__ int   ebuf[KK];
    __shared__ u64   keys[128];
    __shared__ int   s_inds[KK];
    __shared__ float s_vals[KK];
    __shared__ float X1[KK], Y1[KK], X2[KK], Y2[KK], AR[KK];

    f32x4 d[16];
    #pragma unroll
    for (int c = 0; c < 16; c++)
        d[c] = *(const f32x4*)(scb + c*1024 + tid*4);

    #define CNT_GT(T, OUTV) do {                                              \
        int myc_ = 0;                                                         \
        _Pragma("unroll")                                                     \
        for (int c = 0; c < 16; c++) {                                        \
            _Pragma("unroll")                                                 \
            for (int j = 0; j < 4; j++)                                       \
                myc_ += (__float_as_uint(d[c][j]) > (T)) ? 1 : 0;             \
        }                                                                     \
        _Pragma("unroll")                                                     \
        for (int o_ = 32; o_ >= 1; o_ >>= 1) myc_ += __shfl_xor(myc_, o_);    \
        if (lane == 0) red[par][wv] = myc_;                                   \
        __syncthreads();                                                      \
        OUTV = red[par][0] + red[par][1] + red[par][2] + red[par][3];         \
        par ^= 1;                                                             \
    } while (0)

    int par = 0;
    uint Vbits; uint G;
    {
        int tot0; CNT_GT(0u, tot0);
        if (tot0 < KK) { Vbits = 0u; G = (uint)tot0; }
        else {
            uint lo = 0u, hi = 0x7F800000u; int gHi = 0;
            while (hi - lo > 1u) {
                uint mid = lo + ((hi - lo) >> 1);
                int t_; CNT_GT(mid, t_);
                if (t_ >= KK) lo = mid; else { hi = mid; gHi = t_; }
            }
            Vbits = hi; G = (uint)gHi;
        }
    }
    #undef CNT_GT
    const uint Eneed = KK - G;

    f32x4 c4[16];
    #pragma unroll
    for (int c = 0; c < 16; c++)
        c4[c] = *(const f32x4*)(scb + tid*64 + c*4);

    uint cntG = 0, cntE = 0;
    #pragma unroll
    for (int c = 0; c < 16; c++)
        #pragma unroll
        for (int j = 0; j < 4; j++) {
            uint u = __float_as_uint(c4[c][j]);
            cntG += (u > Vbits) ? 1u : 0u;
            cntE += (u == Vbits) ? 1u : 0u;
        }
    uint pk = (cntE << 16) | cntG;
    uint v = pk;
    #pragma unroll
    for (int o = 1; o <= 32; o <<= 1) {
        uint ov = __shfl_up(v, o);
        if (lane >= o) v += ov;
    }
    if (lane == 63) wtot[wv] = v;
    __syncthreads();
    uint woff = 0;
    for (int i = 0; i < 4; i++) if (i < wv) woff += wtot[i];
    uint excl = v - pk + woff;
    uint pG = excl & 0xFFFFu, pE = excl >> 16;

    #pragma unroll
    for (int c = 0; c < 16; c++)
        #pragma unroll
        for (int j = 0; j < 4; j++) {
            uint u = __float_as_uint(c4[c][j]);
            int idx = tid*64 + c*4 + j;
            if (u > Vbits) { gib[pG] = idx; gvb[pG] = u; pG++; }
            else if (u == Vbits) { if (pE < Eneed) ebuf[pE] = idx; pE++; }
        }
    __syncthreads();

    if (tid < 128)
        keys[tid] = (tid < (int)G) ? (((u64)(~gvb[tid]) << 32) | (uint)gib[tid])
                                   : ~0ull;
    for (uint k2 = 2; k2 <= 128; k2 <<= 1) {
        for (uint j = k2 >> 1; j > 0; j >>= 1) {
            __syncthreads();
            if (tid < 128) {
                uint i = (uint)tid, ixj = i ^ j;
                if (ixj > i) {
                    u64 a = keys[i], bb = keys[ixj];
                    bool up = ((i & k2) == 0);
                    if ((a > bb) == up) { keys[i] = bb; keys[ixj] = a; }
                }
            }
        }
    }
    __syncthreads();

    if (tid < KK) {
        if (tid < (int)G) {
            u64 kk2 = keys[tid];
            s_inds[tid] = (int)(uint)kk2;
            s_vals[tid] = __uint_as_float(~(uint)(kk2 >> 32));
        } else {
            s_inds[tid] = ebuf[tid - (int)G];
            s_vals[tid] = __uint_as_float(Vbits);
        }
    }
    __syncthreads();

    if (tid < KK) {  // decode boxes
        int ind   = s_inds[tid];
        float scv = s_vals[tid];
        const float* rb = regp + (size_t)b*2*HWSZ;
        const float* wb = whp  + (size_t)b*2*HWSZ;
        float r0 = rb[ind], r1 = rb[HWSZ + ind];
        float w0 = wb[ind], w1 = wb[HWSZ + ind];
        float ctx = (float)(ind & 127) + r0;
        float cty = (float)(ind >> 7) + r1;
        float x1 = (ctx - w0*0.5f)*4.f, y1 = (cty - w1*0.5f)*4.f;
        float x2 = (ctx + w0*0.5f)*4.f, y2 = (cty + w1*0.5f)*4.f;
        size_t bo = ((size_t)b*KK + tid)*4;
        out[bo+0] = x1; out[bo+1] = y1; out[bo+2] = x2; out[bo+3] = y2;
        out[BN*KK*4 + b*KK + tid]         = (float)cats[(size_t)b*HWSZ + ind];
        out[BN*KK*4 + BN*KK + b*KK + tid] = scv;
        X1[tid] = x1; Y1[tid] = y1; X2[tid] = x2; Y2[tid] = y2;
        AR[tid] = (x2 - x1)*(y2 - y1);
    }
    __syncthreads();

    if (tid < 64) {  // NMS in wave 0
        const int l = tid;
        float x1a = X1[l], y1a = Y1[l], x2a = X2[l], y2a = Y2[l], ara = AR[l];
        int   ka  = (s_vals[l] > 0.2f) ? 1 : 0;
        float x1b = 0, y1b = 0, x2b = 0, y2b = 0, arb = 0;
        int   kb  = 0;
        if (l < KK - 64) {
            x1b = X1[64+l]; y1b = Y1[64+l]; x2b = X2[64+l]; y2b = Y2[64+l];
            arb = AR[64+l];
            kb  = (s_vals[64+l] > 0.2f) ? 1 : 0;
        }
        for (int i = 0; i < KK; i++) {
            float jx1, jy1, jx2, jy2, jar; int jk;
            if (i < 64) {
                jx1 = __shfl(x1a, i); jy1 = __shfl(y1a, i);
                jx2 = __shfl(x2a, i); jy2 = __shfl(y2a, i);
                jar = __shfl(ara, i); jk  = __shfl(ka,  i);
            } else {
                int li = i - 64;
                jx1 = __shfl(x1b, li); jy1 = __shfl(y1b, li);
                jx2 = __shfl(x2b, li); jy2 = __shfl(y2b, li);
                jar = __shfl(arb, li); jk  = __shfl(kb,  li);
            }
            if (jk) {
                if (ka && l > i) {
                    float iw = fminf(jx2, x2a) - fmaxf(jx1, x1a); iw = iw > 0.f ? iw : 0.f;
                    float ih = fminf(jy2, y2a) - fmaxf(jy1, y1a); ih = ih > 0.f ? ih : 0.f;
                    float inter = iw*ih;
                    float iou = inter / (jar + ara - inter + 1e-9f);
                    if (iou > 0.5f) ka = 0;
                }
                if (kb && (64 + l) > i) {
                    float iw = fminf(jx2, x2b) - fmaxf(jx1, x1b); iw = iw > 0.f ? iw : 0.f;
                    float ih = fminf(jy2, y2b) - fmaxf(jy1, y1b); ih = ih > 0.f ? ih : 0.f;
                    float inter = iw*ih;
                    float iou = inter / (jar + arb - inter + 1e-9f);
                    if (iou > 0.5f) kb = 0;
                }
            }
        }
        int koff = BN*KK*4 + 2*BN*KK;
        out[koff + b*KK + l] = ka ? 1.f : 0.f;
        if (l < KK - 64) out[koff + b*KK + 64 + l] = kb ? 1.f : 0.f;
    }
}

// ---------------------------------------------------------------------------
extern "C" void kernel_launch(void* const* d_in, const int* in_sizes, int n_in,
                              void* d_out, int out_size, void* d_ws, size_t ws_size,
                              hipStream_t stream) {
    const float* x      = (const float*)d_in[0];
    const float* cls_w1 = (const float*)d_in[1];
    const float* cls_b1 = (const float*)d_in[2];
    const float* cls_w2 = (const float*)d_in[3];
    const float* cls_b2 = (const float*)d_in[4];
    const float* reg_w1 = (const float*)d_in[5];
    const float* reg_b1 = (const float*)d_in[6];
    const float* reg_w2 = (const float*)d_in[7];
    const float* reg_b2 = (const float*)d_in[8];
    const float* wh_w1  = (const float*)d_in[9];
    const float* wh_b1  = (const float*)d_in[10];
    const float* wh_w2  = (const float*)d_in[11];
    const float* wh_b2  = (const float*)d_in[12];

    float* ws   = (float*)d_ws;
    float* clsb = ws + WS_CLS;
    float* regb = ws + WS_REG;
    float* whb  = ws + WS_WH;
    float* scw  = ws + WS_SC;
    int*   cat  = (int*)(ws + WS_CAT);
    f16*   w1h  = (f16*)(ws + WS_W1H);
    f16*   w1l  = (f16*)(ws + WS_W1L);
    f16*   w2h  = (f16*)(ws + WS_W2H);
    f16*   w2l  = (f16*)(ws + WS_W2L);
    f16*   xth  = (f16*)(ws + WS_XTH);
    f16*   xtl  = (f16*)(ws + WS_XTL);
    f16*   zr   = (f16*)(ws + WS_ZR);
    float* sc1  = ws + WS_SC1;
    int*   cat1 = (int*)(ws + WS_CAT1);
    float* sc2  = ws + WS_SC2;
    int*   cat2 = (int*)(ws + WS_CAT2);
    float* sc3  = ws + WS_SC3;
    int*   cat3 = (int*)(ws + WS_CAT3);
    float* out  = (float*)d_out;

    const bool big = ws_size >= (size_t)WS_END4 * 4u;

    k_prep<<<(3*9*64*64 + 112*64 + 255)/256, 256, 0, stream>>>(
        cls_w1, reg_w1, wh_w1, cls_w2, reg_w2, wh_w2, w1h, w1l, w2h, w2l,
        big ? (float*)(ws + WS_ZR) : (float*)0);
    if (big) {
        k_prepx<<<NREG, 256, 0, stream>>>(x, xth, xtl);
        k_conv<<<dim3(2, 64, 16), 256, 0, stream>>>(
            xth, xtl, zr, w1h, w1l, w2h, w2l, cls_b1, reg_b1, wh_b1,
            cls_b2, reg_b2, wh_b2, clsb, regb, whb);
        k_peaks<<<dim3(8, 16, 4), 256, 0, stream>>>(
            clsb, scw, cat, sc1, cat1, sc2, cat2, sc3, cat3, 20);
        k_merge4<<<256, 256, 0, stream>>>(scw, cat, sc1, cat1, sc2, cat2, sc3, cat3);
    } else {
        k_conv_fb<<<dim3(2, 128, 16), 256, 0, stream>>>(
            x, w1h, w1l, w2h, w2l, cls_b1, reg_b1, wh_b1,
            cls_b2, reg_b2, wh_b2, clsb, regb, whb);
        k_peaks<<<dim3(8, 16, 1), 256, 0, stream>>>(
            clsb, scw, cat, scw, cat, scw, cat, scw, cat, 80);
    }
    k_select<<<16, 256, 0, stream>>>(scw, cat, regb, whb, out);
}

// Round 12
// 427.419 us; speedup vs baseline: 1.3301x; 1.0338x over previous
//
#include <hip/hip_runtime.h>
#include <math.h>

// Problem constants
#define BN 16
#define HWSZ 16384
#define NC 80
#define KK 100

typedef _Float16 f16;
typedef _Float16 f16x2 __attribute__((ext_vector_type(2)));
typedef _Float16 f16x4 __attribute__((ext_vector_type(4)));
typedef _Float16 f16x8 __attribute__((ext_vector_type(8)));
typedef float    f32x4 __attribute__((ext_vector_type(4)));
typedef unsigned int uint;
typedef unsigned long long u64;

// ---- workspace layout (float units) ----
#define WS_CLS   0
#define CLS_SZ   (BN*NC*HWSZ)
#define WS_REG   (WS_CLS + CLS_SZ)
#define REG_SZ   (BN*2*HWSZ)
#define WS_WH    (WS_REG + REG_SZ)
#define WH_SZ    (BN*2*HWSZ)
#define WS_SC    (WS_WH + WH_SZ)
#define SC_SZ    (BN*HWSZ)
#define WS_CAT   (WS_SC + SC_SZ)
#define CAT_SZ   (BN*HWSZ)
#define WS_W1H   (WS_CAT + CAT_SZ)             // f16 3*9*64*64 -> 55296 floats/plane
#define W1F      (110592/2)
#define WS_W1L   (WS_W1H + W1F)
#define WS_W2H   (WS_W1L + W1F)                // f16 112*64 (padded) -> 3584 floats/plane
#define W2F      (7168/2)
#define WS_W2L   (WS_W2H + W2F)
// Pre-split/pre-transposed x in (swizzled) LDS-image layout.
// Region = (b,gy,h,chunk): 66 rows x 32ci f16 = 2112 f16 = 4224 B.
#define NREG     (BN*128*2*2)                  // 8192 regions
#define WS_XTH   (WS_W2L + W2F)
#define XT_F     (NREG*2112/2)
#define WS_XTL   (WS_XTH + XT_F)
#define WS_ZR    (WS_XTL + XT_F)               // 4224 B zero region (f16)
#define ZR_F     1056
// partial peak buffers for class-split k_peaks (quarters 1..3)
#define WS_SC1   (WS_ZR + ZR_F)
#define WS_CAT1  (WS_SC1 + SC_SZ)
#define WS_SC2   (WS_CAT1 + CAT_SZ)
#define WS_CAT2  (WS_SC2 + SC_SZ)
#define WS_SC3   (WS_CAT2 + CAT_SZ)
#define WS_CAT3  (WS_SC3 + SC_SZ)
#define WS_END4  (WS_CAT3 + CAT_SZ)

// scaling: x*16, w*256 -> acc = 4096*true
#define SCL_X   16.0f
#define SCL_W   256.0f
#define INV_ACC (1.0f/4096.0f)

// async global->LDS, 16B per lane (dest = wave-uniform base + lane*16)
#define GL2LDS(g, l) __builtin_amdgcn_global_load_lds( \
    (__attribute__((address_space(1))) unsigned int*)(unsigned long long)(const void*)(g), \
    (__attribute__((address_space(3))) unsigned int*)(unsigned int)(unsigned long long)(void*)(l), \
    16, 0, 0)

// ---------------------------------------------------------------------------
// Prep: split weights to fp16 hi/lo (scaled by 256); zero the zero-region.
// ---------------------------------------------------------------------------
__global__ void k_prep(const float* __restrict__ cw1, const float* __restrict__ rw1,
                       const float* __restrict__ ww1, const float* __restrict__ cw2,
                       const float* __restrict__ rw2, const float* __restrict__ ww2,
                       f16* __restrict__ w1h, f16* __restrict__ w1l,
                       f16* __restrict__ w2h, f16* __restrict__ w2l,
                       float* __restrict__ zr) {
    int idx = blockIdx.x * 256 + threadIdx.x;
    if (idx < 3*9*64*64) {
        int ci = idx & 63, co = (idx >> 6) & 63;
        int s  = (idx >> 12) % 9, br = idx / 36864;
        const float* src = (br == 0) ? cw1 : (br == 1 ? rw1 : ww1);
        float v = src[(co*64 + ci)*9 + s] * SCL_W;
        f16 h = (f16)v;
        w1h[idx] = h; w1l[idx] = (f16)(v - (float)h);
    }
    int j = idx - 3*9*64*64;
    if (j >= 0 && j < 112*64) {
        int ci = j & 63, row = j >> 6;
        float v = 0.f;
        if (row < 80)                    v = cw2[row*64 + ci];
        else if (row < 82)               v = rw2[(row-80)*64 + ci];
        else if (row >= 96 && row < 98)  v = ww2[(row-96)*64 + ci];
        v *= SCL_W;
        f16 h = (f16)v;
        w2h[j] = h; w2l[j] = (f16)(v - (float)h);
    }
    if (zr && idx < ZR_F) zr[idx] = 0.f;
}

// ---------------------------------------------------------------------------
// Pre-split + pre-transpose x into per-(b,gy,h,chunk) regions, with the 16B
// slot swizzle baked into the GLOBAL layout (gl2lds writes linearly, so the
// source permutation IS the LDS permutation).
// ---------------------------------------------------------------------------
__global__ __launch_bounds__(256) void k_prepx(const float* __restrict__ x,
                                               f16* __restrict__ xth,
                                               f16* __restrict__ xtl) {
    const int reg = blockIdx.x;
    const int chunk = reg & 1, hh = (reg >> 1) & 1;
    const int gy = (reg >> 2) & 127, b = reg >> 9;
    __shared__ f16 th[66*72] __attribute__((aligned(16)));
    __shared__ f16 tl[66*72] __attribute__((aligned(16)));
    const int tid = threadIdx.x;
    const float* xb = x + ((size_t)(b*64 + chunk*32))*HWSZ + gy*128;
    #pragma unroll
    for (int it = 0; it < 9; it++) {
        int idx = it*256 + tid;
        if (idx < 2112) {
            int ci = idx / 66, pxi = idx - ci*66;
            int gp = hh*64 - 1 + pxi;
            float v = 0.f;
            if (gp >= 0 && gp < 128) v = xb[(size_t)ci*HWSZ + gp] * SCL_X;
            f16 hv = (f16)v;
            th[pxi*72 + ci] = hv;
            tl[pxi*72 + ci] = (f16)(v - (float)hv);
        }
    }
    __syncthreads();
    f16* oh = xth + (size_t)reg*2112;
    f16* ol = xtl + (size_t)reg*2112;
    {
        int row = tid >> 2, q = tid & 3;
        int sq = q ^ ((row >> 1) & 3);
        *(f16x8*)(oh + row*32 + sq*8) = *(const f16x8*)(th + row*72 + q*8);
        *(f16x8*)(ol + row*32 + sq*8) = *(const f16x8*)(tl + row*72 + q*8);
        if (tid < 8) {
            int u2 = 256 + tid, row2 = u2 >> 2, q2 = u2 & 3;
            int sq2 = q2 ^ ((row2 >> 1) & 3);
            *(f16x8*)(oh + row2*32 + sq2*8) = *(const f16x8*)(th + row2*72 + q2*8);
            *(f16x8*)(ol + row2*32 + sq2*8) = *(const f16x8*)(tl + row2*72 + q2*8);
        }
    }
}

// ---------------------------------------------------------------------------
// Fused MFMA conv, r22: r17 inner loop, but chunk-1 regions 0..2 are staged
// EARLY (7 LDS buffers, 59.1 KB) so their loads complete under COMPUTE(0)'s
// MFMA wall instead of being cold-drained at the mid barrier.  Only region 3
// (read solely by the final r=2 step) is staged late into freed buffer 0,
// its drain covered by COMPUTE(1) r=0,1.  Zero new registers; per-
// accumulator MFMA order identical to r17 -> bit-identical outputs.
// ---------------------------------------------------------------------------
#define ABUF 8448                    // bytes per A buffer (hi 4224 + lo 4224)
__global__ __launch_bounds__(256, 2) void k_conv(
    const f16* __restrict__ xth, const f16* __restrict__ xtl, const f16* __restrict__ zreg,
    const f16* __restrict__ w1h, const f16* __restrict__ w1l,
    const f16* __restrict__ w2h, const f16* __restrict__ w2l,
    const float* __restrict__ b1c, const float* __restrict__ b1r, const float* __restrict__ b1w,
    const float* __restrict__ b2c, const float* __restrict__ b2r, const float* __restrict__ b2w,
    float* __restrict__ cls_o, float* __restrict__ reg_o, float* __restrict__ wh_o)
{
    __shared__ char smem[7*ABUF] __attribute__((aligned(16)));   // 59136 B
    f16* Rh = (f16*)smem;                 // epilogue alias over A buffers
    f16* Rl = (f16*)(smem + 9216);

    // XCD-aware bijective swizzle (2048 % 8 == 0).
    const int p  = blockIdx.x + 2*blockIdx.y + 128*blockIdx.z;
    const int lg = (p & 7)*256 + (p >> 3);
    const int b  = lg >> 7;
    const int y0 = ((lg & 127) >> 1) * 2;      // rows y0, y0+1
    const int h  = lg & 1;

    const int tid = threadIdx.x;
    const int w = tid >> 6, lane = tid & 63;
    const int l15 = lane & 15, quad = lane >> 4;
    const int co = w*16 + l15;

    // stage one region (chunk ch, gy index gyi) into LDS buffer bufi
    #define STAGE1(ch, gyi, bufi) do {                                        \
        const int gy_ = y0 - 1 + (gyi);                                       \
        const f16* sh_; const f16* sl_;                                       \
        if (gy_ >= 0 && gy_ < 128) {                                          \
            size_t ro_ = (size_t)(((b*128 + gy_)*2 + h)*2 + (ch)) * 2112;     \
            sh_ = xth + ro_; sl_ = xtl + ro_;                                 \
        } else { sh_ = zreg; sl_ = zreg; }                                    \
        char* db_ = smem + (bufi)*ABUF;                                       \
        GL2LDS(sh_ + tid*8, db_ + tid*16);                                    \
        GL2LDS(sl_ + tid*8, db_ + 4224 + tid*16);                             \
        if (tid < 8) {                                                        \
            GL2LDS(sh_ + 2048 + tid*8, db_ + 4096 + tid*16);                  \
            GL2LDS(sl_ + 2048 + tid*8, db_ + 4224 + 4096 + tid*16);           \
        }                                                                     \
    } while (0)

    f32x4 accA[3][4], accB[3][4];
    #pragma unroll
    for (int br = 0; br < 3; br++)
        #pragma unroll
        for (int m = 0; m < 4; m++) {
            accA[br][m] = (f32x4){0.f,0.f,0.f,0.f};
            accB[br][m] = (f32x4){0.f,0.f,0.f,0.f};
        }

    // one (r,dx-sweep) step: row0 uses buffer A0, row1 uses buffer A1,
    // B fragments from chunk ph / spatial row rr.  r17's verified body.
    #define CSTEP(ph, rr, A0p, A1p) do {                                      \
        const f16* A0 = (const f16*)(A0p);                                    \
        const f16* A1 = (const f16*)(A1p);                                    \
        _Pragma("unroll")                                                     \
        for (int dx = 0; dx < 3; dx++) {                                      \
            const int s = (rr)*3 + dx;                                        \
            f16x8 bh[3], bl[3];                                               \
            _Pragma("unroll")                                                 \
            for (int br = 0; br < 3; br++) {                                  \
                size_t k = ((size_t)((br*9 + s)*64 + co))*64 + (ph)*32 + quad*8; \
                bh[br] = *(const f16x8*)(w1h + k);                            \
                bl[br] = *(const f16x8*)(w1l + k);                            \
            }                                                                 \
            _Pragma("unroll")                                                 \
            for (int m = 0; m < 4; m++) {                                     \
                const int row = m*16 + l15 + dx;                              \
                const int off = row*32 + ((quad ^ ((row >> 1) & 3)) << 3);    \
                {                                                             \
                    f16x8 ah0 = *(const f16x8*)(A0 + off);                    \
                    f16x8 al0 = *(const f16x8*)(A0 + 2112 + off);             \
                    _Pragma("unroll")                                         \
                    for (int br = 0; br < 3; br++) {                          \
                        accA[br][m] = __builtin_amdgcn_mfma_f32_16x16x32_f16(ah0, bh[br], accA[br][m], 0,0,0); \
                        accA[br][m] = __builtin_amdgcn_mfma_f32_16x16x32_f16(ah0, bl[br], accA[br][m], 0,0,0); \
                        accA[br][m] = __builtin_amdgcn_mfma_f32_16x16x32_f16(al0, bh[br], accA[br][m], 0,0,0); \
                    }                                                         \
                }                                                             \
                {                                                             \
                    f16x8 ah1 = *(const f16x8*)(A1 + off);                    \
                    f16x8 al1 = *(const f16x8*)(A1 + 2112 + off);             \
                    _Pragma("unroll")                                         \
                    for (int br = 0; br < 3; br++) {                          \
                        accB[br][m] = __builtin_amdgcn_mfma_f32_16x16x32_f16(ah1, bh[br], accB[br][m], 0,0,0); \
                        accB[br][m] = __builtin_amdgcn_mfma_f32_16x16x32_f16(ah1, bl[br], accB[br][m], 0,0,0); \
                        accB[br][m] = __builtin_amdgcn_mfma_f32_16x16x32_f16(al1, bh[br], accB[br][m], 0,0,0); \
                    }                                                         \
                }                                                             \
            }                                                                 \
        }                                                                     \
    } while (0)

    // prologue: chunk0 regions 0-3 -> bufs 0-3, chunk1 regions 0-2 -> bufs 4-6
    #pragma unroll
    for (int gyi = 0; gyi < 4; gyi++) STAGE1(0, gyi, gyi);
    #pragma unroll
    for (int gyi = 0; gyi < 3; gyi++) STAGE1(1, gyi, 4 + gyi);
    __syncthreads();        // bufs 0-6 resident

    // chunk 0 (runtime r loop, same codegen shape as r17)
    for (int r = 0; r < 3; r++)
        CSTEP(0, r, smem + r*ABUF, smem + (r+1)*ABUF);

    __syncthreads();        // chunk-0 reads done -> buffer 0 reusable
    STAGE1(1, 3, 0);        // late single region; drain covered by r=0,1 below

    // chunk 1, r = 0,1 (bufs 4,5,6 — untouched by the late stage)
    for (int r = 0; r < 2; r++)
        CSTEP(1, r, smem + (4+r)*ABUF, smem + (5+r)*ABUF);

    __syncthreads();        // buffer 0 resident (2 loads, ~2 CSTEPs old)
    CSTEP(1, 2, smem + 6*ABUF, smem + 0*ABUF);

    #undef STAGE1
    #undef CSTEP

    // ======================= epilogue: per branch x per row =======================
    #define EPIROW(ACC, yy) do {                                              \
        __syncthreads();              /* prior A/conv2 reads done */          \
        _Pragma("unroll")                                                     \
        for (int m = 0; m < 4; m++)                                           \
            _Pragma("unroll")                                                 \
            for (int rg = 0; rg < 4; rg++) {                                  \
                float t = fmaxf(ACC[br][m][rg]*INV_ACC + b1v, 0.f) * SCL_X;   \
                f16 hh = (f16)t;                                              \
                int pxl = m*16 + quad*4 + rg;                                 \
                Rh[pxl*72 + co] = hh;                                         \
                Rl[pxl*72 + co] = (f16)(t - (float)hh);                       \
            }                                                                 \
        __syncthreads();                                                      \
        const int NT     = (br == 0) ? 5 : 1;                                 \
        const int rowoff = (br == 0) ? 0 : (br == 1 ? 80 : 96);               \
        f32x4 a2[5];                                                          \
        _Pragma("unroll")                                                     \
        for (int n = 0; n < 5; n++) a2[n] = (f32x4){0.f,0.f,0.f,0.f};         \
        _Pragma("unroll")                                                     \
        for (int kc = 0; kc < 64; kc += 32) {                                 \
            int off = co*72 + kc + quad*8;                                    \
            f16x8 xh = *(const f16x8*)(Rh + off);                             \
            f16x8 xl = *(const f16x8*)(Rl + off);                             \
            _Pragma("unroll")                                                 \
            for (int n = 0; n < 5; n++) {                                     \
                if (n >= NT) break;                                           \
                const f16* g2h = w2h + (rowoff + n*16 + l15)*64 + kc + quad*8;\
                const f16* g2l = w2l + (rowoff + n*16 + l15)*64 + kc + quad*8;\
                f16x8 bh2 = *(const f16x8*)g2h;                               \
                f16x8 bl2 = *(const f16x8*)g2l;                               \
                a2[n] = __builtin_amdgcn_mfma_f32_16x16x32_f16(xh, bh2, a2[n], 0,0,0); \
                a2[n] = __builtin_amdgcn_mfma_f32_16x16x32_f16(xh, bl2, a2[n], 0,0,0); \
                a2[n] = __builtin_amdgcn_mfma_f32_16x16x32_f16(xl, bh2, a2[n], 0,0,0); \
            }                                                                 \
        }                                                                     \
        const int pxg = h*64 + w*16 + quad*4;                                 \
        if (br == 0) {                                                        \
            _Pragma("unroll")                                                 \
            for (int n = 0; n < 5; n++) {                                     \
                int co2 = n*16 + l15;                                         \
                float bb = b2c[co2];                                          \
                _Pragma("unroll")                                             \
                for (int rg = 0; rg < 4; rg++) {                              \
                    float sv = a2[n][rg]*INV_ACC + bb;                        \
                    cls_o[((size_t)(b*80 + co2)*128 + (yy))*128 + pxg + rg] = 1.f/(1.f + expf(-sv)); \
                }                                                             \
            }                                                                 \
        } else {                                                              \
            if (l15 < 2) {                                                    \
                const float* b2 = (br == 1) ? b2r : b2w;                      \
                float* outp     = (br == 1) ? reg_o : wh_o;                   \
                float bb = b2[l15];                                           \
                _Pragma("unroll")                                             \
                for (int rg = 0; rg < 4; rg++) {                              \
                    float sv = a2[0][rg]*INV_ACC + bb;                        \
                    float o  = (br == 1) ? (1.f/(1.f + expf(-sv))) : expf(sv);\
                    outp[((size_t)(b*2 + l15))*HWSZ + (yy)*128 + pxg + rg] = o; \
                }                                                             \
            }                                                                 \
        }                                                                     \
    } while (0)

    #pragma unroll
    for (int br = 0; br < 3; br++) {
        const float* b1 = (br == 0) ? b1c : (br == 1 ? b1r : b1w);
        const float b1v = b1[co];
        EPIROW(accA, y0);
        EPIROW(accB, y0 + 1);
    }
    #undef EPIROW
}

// ---------------------------------------------------------------------------
// Fallback conv (r11 kernel) — used only if ws_size can't hold the pre-split
// x planes.  Bit-identical outputs to k_conv.
// ---------------------------------------------------------------------------
#define A_STRIDE 36
#define ABUF_FB  9504
__global__ __launch_bounds__(256) void k_conv_fb(
    const float* __restrict__ x,
    const f16* __restrict__ w1h, const f16* __restrict__ w1l,
    const f16* __restrict__ w2h, const f16* __restrict__ w2l,
    const float* __restrict__ b1c, const float* __restrict__ b1r, const float* __restrict__ b1w,
    const float* __restrict__ b2c, const float* __restrict__ b2r, const float* __restrict__ b2w,
    float* __restrict__ cls_o, float* __restrict__ reg_o, float* __restrict__ wh_o)
{
    __shared__ char smem[19008] __attribute__((aligned(16)));
    f16* Rh = (f16*)smem;
    f16* Rl = (f16*)(smem + 9216);

    const int h = blockIdx.x, y = blockIdx.y, b = blockIdx.z;
    const int tid = threadIdx.x;
    const int w = tid >> 6, lane = tid & 63;
    const int l15 = lane & 15, quad = lane >> 4;

    static const int CS[6] = {0,0,0,1,1,1};
    static const int RS[6] = {0,1,2,0,1,2};

    #define STAGEF(bufi, si_) do {                                            \
        const int gy = y - 1 + RS[si_];                                       \
        const bool ok = (gy >= 0) && (gy < 128);                              \
        const float* xp = x + ((size_t)(b*64 + CS[si_]*32)*128 + gy)*128;     \
        f16x2* dh = (f16x2*)(smem + (bufi)*ABUF_FB);                          \
        f16x2* dl = (f16x2*)(smem + (bufi)*ABUF_FB + 4752);                   \
        _Pragma("unroll")                                                     \
        for (int e0 = 0; e0 < 1024; e0 += 256) {                              \
            int e = e0 + tid;                                                 \
            int pxl = e & 63, cp = e >> 6;                                    \
            float v0 = 0.f, v1 = 0.f;                                         \
            if (ok) { int g = h*64 + pxl;                                     \
                      v0 = xp[(size_t)(2*cp)*HWSZ + g]*SCL_X;                 \
                      v1 = xp[(size_t)(2*cp+1)*HWSZ + g]*SCL_X; }             \
            f16 h0 = (f16)v0, h1 = (f16)v1;                                   \
            f16 l0 = (f16)(v0 - (float)h0), l1 = (f16)(v1 - (float)h1);       \
            int wi = (pxl + 1)*18 + cp;                                       \
            dh[wi] = (f16x2){h0, h1};                                         \
            dl[wi] = (f16x2){l0, l1};                                         \
        }                                                                     \
        if (tid < 32) {                                                       \
            int side = tid >> 4, cp = tid & 15;                               \
            bool valid = ok && (side ? (h == 0) : (h == 1));                  \
            int g = side ? 64 : 63;                                           \
            float v0 = 0.f, v1 = 0.f;                                         \
            if (valid) { v0 = xp[(size_t)(2*cp)*HWSZ + g]*SCL_X;              \
                         v1 = xp[(size_t)(2*cp+1)*HWSZ + g]*SCL_X; }          \
            f16 h0 = (f16)v0, h1 = (f16)v1;                                   \
            f16 l0 = (f16)(v0 - (float)h0), l1 = (f16)(v1 - (float)h1);       \
            int wi = (side ? 65 : 0)*18 + cp;                                 \
            dh[wi] = (f16x2){h0, h1};                                         \
            dl[wi] = (f16x2){l0, l1};                                         \
        }                                                                     \
    } while (0)

    f32x4 acc[3][4];
    #pragma unroll
    for (int br = 0; br < 3; br++)
        #pragma unroll
        for (int m = 0; m < 4; m++) acc[br][m] = (f32x4){0.f,0.f,0.f,0.f};

    STAGEF(0, 0);
    __syncthreads();

    for (int si = 0; si < 6; si++) {
        const int cur = si & 1;
        if (si < 5) STAGEF(cur ^ 1, si + 1);
        const f16* APh = (const f16*)(smem + cur*ABUF_FB);
        const f16* APl = APh + 2376;
        const int chunk = CS[si], r = RS[si];
        #pragma unroll
        for (int dx = 0; dx < 3; dx++) {
            const int s = r*3 + dx;
            f16x8 bh[3], bl[3];
            #pragma unroll
            for (int br = 0; br < 3; br++) {
                size_t k = ((size_t)((br*9 + s)*64 + (w*16 + l15)))*64 + chunk*32 + quad*8;
                bh[br] = *(const f16x8*)(w1h + k);
                bl[br] = *(const f16x8*)(w1l + k);
            }
            #pragma unroll
            for (int m = 0; m < 4; m++) {
                int off = (m*16 + l15 + dx)*A_STRIDE + quad*8;
                f16x4 h0 = *(const f16x4*)(APh + off);
                f16x4 h1 = *(const f16x4*)(APh + off + 4);
                f16x4 u0 = *(const f16x4*)(APl + off);
                f16x4 u1 = *(const f16x4*)(APl + off + 4);
                f16x8 ah = __builtin_shufflevector(h0, h1, 0,1,2,3,4,5,6,7);
                f16x8 al = __builtin_shufflevector(u0, u1, 0,1,2,3,4,5,6,7);
                #pragma unroll
                for (int br = 0; br < 3; br++) {
                    acc[br][m] = __builtin_amdgcn_mfma_f32_16x16x32_f16(ah, bh[br], acc[br][m], 0,0,0);
                    acc[br][m] = __builtin_amdgcn_mfma_f32_16x16x32_f16(ah, bl[br], acc[br][m], 0,0,0);
                    acc[br][m] = __builtin_amdgcn_mfma_f32_16x16x32_f16(al, bh[br], acc[br][m], 0,0,0);
                }
            }
        }
        __syncthreads();
    }
    #undef STAGEF

    #pragma unroll
    for (int br = 0; br < 3; br++) {
        const float* b1 = (br == 0) ? b1c : (br == 1 ? b1r : b1w);
        const float b1v = b1[w*16 + l15];
        __syncthreads();
        #pragma unroll
        for (int m = 0; m < 4; m++)
            #pragma unroll
            for (int rg = 0; rg < 4; rg++) {
                float t = fmaxf(acc[br][m][rg]*INV_ACC + b1v, 0.f) * SCL_X;
                f16 hh = (f16)t;
                int pxl = m*16 + quad*4 + rg;
                int co  = w*16 + l15;
                Rh[pxl*72 + co] = hh;
                Rl[pxl*72 + co] = (f16)(t - (float)hh);
            }
        __syncthreads();

        const int NT     = (br == 0) ? 5 : 1;
        const int rowoff = (br == 0) ? 0 : (br == 1 ? 80 : 96);
        f32x4 a2[5];
        #pragma unroll
        for (int n = 0; n < 5; n++) a2[n] = (f32x4){0.f,0.f,0.f,0.f};

        #pragma unroll
        for (int kc = 0; kc < 64; kc += 32) {
            int off = (w*16 + l15)*72 + kc + quad*8;
            f16x8 xh = *(const f16x8*)(Rh + off);
            f16x8 xl = *(const f16x8*)(Rl + off);
            #pragma unroll
            for (int n = 0; n < 5; n++) {
                if (n >= NT) break;
                const f16* g2h = w2h + (rowoff + n*16 + l15)*64 + kc + quad*8;
                const f16* g2l = w2l + (rowoff + n*16 + l15)*64 + kc + quad*8;
                f16x8 bh = *(const f16x8*)g2h;
                f16x8 bl = *(const f16x8*)g2l;
                a2[n] = __builtin_amdgcn_mfma_f32_16x16x32_f16(xh, bh, a2[n], 0,0,0);
                a2[n] = __builtin_amdgcn_mfma_f32_16x16x32_f16(xh, bl, a2[n], 0,0,0);
                a2[n] = __builtin_amdgcn_mfma_f32_16x16x32_f16(xl, bh, a2[n], 0,0,0);
            }
        }

        const int pxg = h*64 + w*16 + quad*4;
        if (br == 0) {
            #pragma unroll
            for (int n = 0; n < 5; n++) {
                int co2 = n*16 + l15;
                float bb = b2c[co2];
                #pragma unroll
                for (int rg = 0; rg < 4; rg++) {
                    float sv = a2[n][rg]*INV_ACC + bb;
                    cls_o[((size_t)(b*80 + co2)*128 + y)*128 + pxg + rg] = 1.f/(1.f + expf(-sv));
                }
            }
        } else {
            if (l15 < 2) {
                const float* b2 = (br == 1) ? b2r : b2w;
                float* outp     = (br == 1) ? reg_o : wh_o;
                float bb = b2[l15];
                #pragma unroll
                for (int rg = 0; rg < 4; rg++) {
                    float sv = a2[0][rg]*INV_ACC + bb;
                    float o  = (br == 1) ? (1.f/(1.f + expf(-sv))) : expf(sv);
                    outp[((size_t)(b*2 + l15))*HWSZ + y*128 + pxg + rg] = o;
                }
            }
        }
    }
}

// ---------------------------------------------------------------------------
// 3x3 peak mask + max/argmax over a CLASS RANGE, r22: 8 rows per wave — 10
// row loads serve 8 output rows (vertical traffic 1.5x -> 1.25x).  fmax
// argument order per row preserved exactly -> bit-identical.
// grid (4, 16, 4) span 20; fallback (4, 16, 1) span 80.
// ---------------------------------------------------------------------------
__global__ __launch_bounds__(256) void k_peaks(const float* __restrict__ cls,
                                               float* __restrict__ scA, int* __restrict__ catA,
                                               float* __restrict__ scB, int* __restrict__ catB,
                                               float* __restrict__ scC, int* __restrict__ catC,
                                               float* __restrict__ scD, int* __restrict__ catD,
                                               int span) {
    const int b  = blockIdx.y;
    const int z  = blockIdx.z;
    const int c0 = z * span, c1 = c0 + span;
    float* __restrict__ sc  = (z == 0) ? scA  : (z == 1) ? scB  : (z == 2) ? scC  : scD;
    int*   __restrict__ cat = (z == 0) ? catA : (z == 1) ? catB : (z == 2) ? catC : catD;
    const int wv = threadIdx.x >> 6;
    const int l  = threadIdx.x & 63;
    const int y0 = blockIdx.x * 32 + wv * 8;    // rows y0 .. y0+7
    const int p0 = l * 2;
    const bool gt = (y0 > 0);                   // row y0-1 exists
    const bool gb = (y0 + 8 < 128);             // row y0+8 exists
    float best[16]; int bc[16];
    #pragma unroll
    for (int i = 0; i < 16; i++) { best[i] = -1.f; bc[i] = c0; }
    for (int c = c0; c < c1; c++) {
        const float* pl = cls + (size_t)(b*80 + c)*HWSZ + y0*128 + p0;
        float2 t[10];
        t[0] = gt ? *(const float2*)(pl - 128) : make_float2(-1e30f, -1e30f);
        #pragma unroll
        for (int i = 0; i < 8; i++) t[i+1] = *(const float2*)(pl + i*128);
        t[9] = gb ? *(const float2*)(pl + 8*128) : make_float2(-1e30f, -1e30f);
        #pragma unroll
        for (int i = 0; i < 8; i++) {
            // row y0+i: cur=t[i+1], tp=t[i], bt=t[i+2] — same fmax order
            float vm0 = fmaxf(t[i+1].x, fmaxf(t[i].x, t[i+2].x));
            float vm1 = fmaxf(t[i+1].y, fmaxf(t[i].y, t[i+2].y));
            float lft = __shfl_up(vm1, 1);   if (l == 0)  lft = -1e30f;
            float rgt = __shfl_down(vm0, 1); if (l == 63) rgt = -1e30f;
            float m0 = fmaxf(lft, fmaxf(vm0, vm1));
            float m1 = fmaxf(vm0, fmaxf(vm1, rgt));
            float k0 = (t[i+1].x == m0) ? t[i+1].x : 0.f;
            float k1 = (t[i+1].y == m1) ? t[i+1].y : 0.f;
            if (k0 > best[2*i])   { best[2*i]   = k0; bc[2*i]   = c; }
            if (k1 > best[2*i+1]) { best[2*i+1] = k1; bc[2*i+1] = c; }
        }
    }
    #pragma unroll
    for (int i = 0; i < 8; i++) {
        int o = b*HWSZ + (y0 + i)*128 + p0;
        *(float2*)&sc[o] = make_float2(best[2*i], best[2*i+1]);
        *(int2*)&cat[o]  = make_int2(bc[2*i], bc[2*i+1]);
    }
}

// ---------------------------------------------------------------------------
// Merge the 4 class-quarter partials into sc0/cat0 in place (strict > ->
// lowest class index wins ties == exact argmax).
// ---------------------------------------------------------------------------
__global__ __launch_bounds__(256) void k_merge4(float* __restrict__ sc0, int* __restrict__ cat0,
                                                const float* __restrict__ s1, const int* __restrict__ c1,
                                                const float* __restrict__ s2, const int* __restrict__ c2,
                                                const float* __restrict__ s3, const int* __restrict__ c3) {
    int i = (blockIdx.x * 256 + threadIdx.x) * 4;
    float4 a = *(const float4*)(sc0 + i);
    int4   ca = *(const int4*)(cat0 + i);
    {
        float4 bq = *(const float4*)(s1 + i);
        int4   cb = *(const int4*)(c1 + i);
        if (bq.x > a.x) { a.x = bq.x; ca.x = cb.x; }
        if (bq.y > a.y) { a.y = bq.y; ca.y = cb.y; }
        if (bq.z > a.z) { a.z = bq.z; ca.z = cb.z; }
        if (bq.w > a.w) { a.w = bq.w; ca.w = cb.w; }
    }
    {
        float4 bq = *(const float4*)(s2 + i);
        int4   cb = *(const int4*)(c2 + i);
        if (bq.x > a.x) { a.x = bq.x; ca.x = cb.x; }
        if (bq.y > a.y) { a.y = bq.y; ca.y = cb.y; }
        if (bq.z > a.z) { a.z = bq.z; ca.z = cb.z; }
        if (bq.w > a.w) { a.w = bq.w; ca.w = cb.w; }
    }
    {
        float4 bq = *(const float4*)(s3 + i);
        int4   cb = *(const int4*)(c3 + i);
        if (bq.x > a.x) { a.x = bq.x; ca.x = cb.x; }
        if (bq.y > a.y) { a.y = bq.y; ca.y = cb.y; }
        if (bq.z > a.z) { a.z = bq.z; ca.z = cb.z; }
        if (bq.w > a.w) { a.w = bq.w; ca.w = cb.w; }
    }
    *(float4*)(sc0 + i) = a;
    *(int4*)(cat0 + i)  = ca;
}

// ---------------------------------------------------------------------------
// k_select (verified r14): top-100 via integer bisection on float bits,
// deterministic index-ordered collect, 128-wide bitonic sort on
// (~valbits, idx) == (value desc, index asc) — exactly lax.top_k's order.
// Then box decode + NMS.
// ---------------------------------------------------------------------------
__global__ __launch_bounds__(256) void k_select(const float* __restrict__ sc,
                                                const int* __restrict__ cats,
                                                const float* __restrict__ regp,
                                                const float* __restrict__ whp,
                                                float* __restrict__ out) {
    const int b   = blockIdx.x;
    const int tid = threadIdx.x;
    const int wv  = tid >> 6, lane = tid & 63;
    const float* scb = sc + (size_t)b*HWSZ;

    __shared__ int   red[2][4];
    __shared__ uint  wtot[4];
    __shared__ int   gib[128];
    __shared__ uint  gvb[128];
    __shared__ int   ebuf[KK];
    __shared__ u64   keys[128];
    __shared__ int   s_inds[KK];
    __shared__ float s_vals[KK];
    __shared__ float X1[KK], Y1[KK], X2[KK], Y2[KK], AR[KK];

    f32x4 d[16];
    #pragma unroll
    for (int c = 0; c < 16; c++)
        d[c] = *(const f32x4*)(scb + c*1024 + tid*4);

    #define CNT_GT(T, OUTV) do {                                              \
        int myc_ = 0;                                                         \
        _Pragma("unroll")                                                     \
        for (int c = 0; c < 16; c++) {                                        \
            _Pragma("unroll")                                                 \
            for (int j = 0; j < 4; j++)                                       \
                myc_ += (__float_as_uint(d[c][j]) > (T)) ? 1 : 0;             \
        }                                                                     \
        _Pragma("unroll")                                                     \
        for (int o_ = 32; o_ >= 1; o_ >>= 1) myc_ += __shfl_xor(myc_, o_);    \
        if (lane == 0) red[par][wv] = myc_;                                   \
        __syncthreads();                                                      \
        OUTV = red[par][0] + red[par][1] + red[par][2] + red[par][3];         \
        par ^= 1;                                                             \
    } while (0)

    int par = 0;
    uint Vbits; uint G;
    {
        int tot0; CNT_GT(0u, tot0);
        if (tot0 < KK) { Vbits = 0u; G = (uint)tot0; }
        else {
            uint lo = 0u, hi = 0x7F800000u; int gHi = 0;
            while (hi - lo > 1u) {
                uint mid = lo + ((hi - lo) >> 1);
                int t_; CNT_GT(mid, t_);
                if (t_ >= KK) lo = mid; else { hi = mid; gHi = t_; }
            }
            Vbits = hi; G = (uint)gHi;
        }
    }
    #undef CNT_GT
    const uint Eneed = KK - G;

    f32x4 c4[16];
    #pragma unroll
    for (int c = 0; c < 16; c++)
        c4[c] = *(const f32x4*)(scb + tid*64 + c*4);

    uint cntG = 0, cntE = 0;
    #pragma unroll
    for (int c = 0; c < 16; c++)
        #pragma unroll
        for (int j = 0; j < 4; j++) {
            uint u = __float_as_uint(c4[c][j]);
            cntG += (u > Vbits) ? 1u : 0u;
            cntE += (u == Vbits) ? 1u : 0u;
        }
    uint pk = (cntE << 16) | cntG;
    uint v = pk;
    #pragma unroll
    for (int o = 1; o <= 32; o <<= 1) {
        uint ov = __shfl_up(v, o);
        if (lane >= o) v += ov;
    }
    if (lane == 63) wtot[wv] = v;
    __syncthreads();
    uint woff = 0;
    for (int i = 0; i < 4; i++) if (i < wv) woff += wtot[i];
    uint excl = v - pk + woff;
    uint pG = excl & 0xFFFFu, pE = excl >> 16;

    #pragma unroll
    for (int c = 0; c < 16; c++)
        #pragma unroll
        for (int j = 0; j < 4; j++) {
            uint u = __float_as_uint(c4[c][j]);
            int idx = tid*64 + c*4 + j;
            if (u > Vbits) { gib[pG] = idx; gvb[pG] = u; pG++; }
            else if (u == Vbits) { if (pE < Eneed) ebuf[pE] = idx; pE++; }
        }
    __syncthreads();

    if (tid < 128)
        keys[tid] = (tid < (int)G) ? (((u64)(~gvb[tid]) << 32) | (uint)gib[tid])
                                   : ~0ull;
    for (uint k2 = 2; k2 <= 128; k2 <<= 1) {
        for (uint j = k2 >> 1; j > 0; j >>= 1) {
            __syncthreads();
            if (tid < 128) {
                uint i = (uint)tid, ixj = i ^ j;
                if (ixj > i) {
                    u64 a = keys[i], bb = keys[ixj];
                    bool up = ((i & k2) == 0);
                    if ((a > bb) == up) { keys[i] = bb; keys[ixj] = a; }
                }
            }
        }
    }
    __syncthreads();

    if (tid < KK) {
        if (tid < (int)G) {
            u64 kk2 = keys[tid];
            s_inds[tid] = (int)(uint)kk2;
            s_vals[tid] = __uint_as_float(~(uint)(kk2 >> 32));
        } else {
            s_inds[tid] = ebuf[tid - (int)G];
            s_vals[tid] = __uint_as_float(Vbits);
        }
    }
    __syncthreads();

    if (tid < KK) {  // decode boxes
        int ind   = s_inds[tid];
        float scv = s_vals[tid];
        const float* rb = regp + (size_t)b*2*HWSZ;
        const float* wb = whp  + (size_t)b*2*HWSZ;
        float r0 = rb[ind], r1 = rb[HWSZ + ind];
        float w0 = wb[ind], w1 = wb[HWSZ + ind];
        float ctx = (float)(ind & 127) + r0;
        float cty = (float)(ind >> 7) + r1;
        float x1 = (ctx - w0*0.5f)*4.f, y1 = (cty - w1*0.5f)*4.f;
        float x2 = (ctx + w0*0.5f)*4.f, y2 = (cty + w1*0.5f)*4.f;
        size_t bo = ((size_t)b*KK + tid)*4;
        out[bo+0] = x1; out[bo+1] = y1; out[bo+2] = x2; out[bo+3] = y2;
        out[BN*KK*4 + b*KK + tid]         = (float)cats[(size_t)b*HWSZ + ind];
        out[BN*KK*4 + BN*KK + b*KK + tid] = scv;
        X1[tid] = x1; Y1[tid] = y1; X2[tid] = x2; Y2[tid] = y2;
        AR[tid] = (x2 - x1)*(y2 - y1);
    }
    __syncthreads();

    if (tid < 64) {  // NMS in wave 0
        const int l = tid;
        float x1a = X1[l], y1a = Y1[l], x2a = X2[l], y2a = Y2[l], ara = AR[l];
        int   ka  = (s_vals[l] > 0.2f) ? 1 : 0;
        float x1b = 0, y1b = 0, x2b = 0, y2b = 0, arb = 0;
        int   kb  = 0;
        if (l < KK - 64) {
            x1b = X1[64+l]; y1b = Y1[64+l]; x2b = X2[64+l]; y2b = Y2[64+l];
            arb = AR[64+l];
            kb  = (s_vals[64+l] > 0.2f) ? 1 : 0;
        }
        for (int i = 0; i < KK; i++) {
            float jx1, jy1, jx2, jy2, jar; int jk;
            if (i < 64) {
                jx1 = __shfl(x1a, i); jy1 = __shfl(y1a, i);
                jx2 = __shfl(x2a, i); jy2 = __shfl(y2a, i);
                jar = __shfl(ara, i); jk  = __shfl(ka,  i);
            } else {
                int li = i - 64;
                jx1 = __shfl(x1b, li); jy1 = __shfl(y1b, li);
                jx2 = __shfl(x2b, li); jy2 = __shfl(y2b, li);
                jar = __shfl(arb, li); jk  = __shfl(kb,  li);
            }
            if (jk) {
                if (ka && l > i) {
                    float iw = fminf(jx2, x2a) - fmaxf(jx1, x1a); iw = iw > 0.f ? iw : 0.f;
                    float ih = fminf(jy2, y2a) - fmaxf(jy1, y1a); ih = ih > 0.f ? ih : 0.f;
                    float inter = iw*ih;
                    float iou = inter / (jar + ara - inter + 1e-9f);
                    if (iou > 0.5f) ka = 0;
                }
                if (kb && (64 + l) > i) {
                    float iw = fminf(jx2, x2b) - fmaxf(jx1, x1b); iw = iw > 0.f ? iw : 0.f;
                    float ih = fminf(jy2, y2b) - fmaxf(jy1, y1b); ih = ih > 0.f ? ih : 0.f;
                    float inter = iw*ih;
                    float iou = inter / (jar + arb - inter + 1e-9f);
                    if (iou > 0.5f) kb = 0;
                }
            }
        }
        int koff = BN*KK*4 + 2*BN*KK;
        out[koff + b*KK + l] = ka ? 1.f : 0.f;
        if (l < KK - 64) out[koff + b*KK + 64 + l] = kb ? 1.f : 0.f;
    }
}

// ---------------------------------------------------------------------------
extern "C" void kernel_launch(void* const* d_in, const int* in_sizes, int n_in,
                              void* d_out, int out_size, void* d_ws, size_t ws_size,
                              hipStream_t stream) {
    const float* x      = (const float*)d_in[0];
    const float* cls_w1 = (const float*)d_in[1];
    const float* cls_b1 = (const float*)d_in[2];
    const float* cls_w2 = (const float*)d_in[3];
    const float* cls_b2 = (const float*)d_in[4];
    const float* reg_w1 = (const float*)d_in[5];
    const float* reg_b1 = (const float*)d_in[6];
    const float* reg_w2 = (const float*)d_in[7];
    const float* reg_b2 = (const float*)d_in[8];
    const float* wh_w1  = (const float*)d_in[9];
    const float* wh_b1  = (const float*)d_in[10];
    const float* wh_w2  = (const float*)d_in[11];
    const float* wh_b2  = (const float*)d_in[12];

    float* ws   = (float*)d_ws;
    float* clsb = ws + WS_CLS;
    float* regb = ws + WS_REG;
    float* whb  = ws + WS_WH;
    float* scw  = ws + WS_SC;
    int*   cat  = (int*)(ws + WS_CAT);
    f16*   w1h  = (f16*)(ws + WS_W1H);
    f16*   w1l  = (f16*)(ws + WS_W1L);
    f16*   w2h  = (f16*)(ws + WS_W2H);
    f16*   w2l  = (f16*)(ws + WS_W2L);
    f16*   xth  = (f16*)(ws + WS_XTH);
    f16*   xtl  = (f16*)(ws + WS_XTL);
    f16*   zr   = (f16*)(ws + WS_ZR);
    float* sc1  = ws + WS_SC1;
    int*   cat1 = (int*)(ws + WS_CAT1);
    float* sc2  = ws + WS_SC2;
    int*   cat2 = (int*)(ws + WS_CAT2);
    float* sc3  = ws + WS_SC3;
    int*   cat3 = (int*)(ws + WS_CAT3);
    float* out  = (float*)d_out;

    const bool big = ws_size >= (size_t)WS_END4 * 4u;

    k_prep<<<(3*9*64*64 + 112*64 + 255)/256, 256, 0, stream>>>(
        cls_w1, reg_w1, wh_w1, cls_w2, reg_w2, wh_w2, w1h, w1l, w2h, w2l,
        big ? (float*)(ws + WS_ZR) : (float*)0);
    if (big) {
        k_prepx<<<NREG, 256, 0, stream>>>(x, xth, xtl);
        k_conv<<<dim3(2, 64, 16), 256, 0, stream>>>(
            xth, xtl, zr, w1h, w1l, w2h, w2l, cls_b1, reg_b1, wh_b1,
            cls_b2, reg_b2, wh_b2, clsb, regb, whb);
        k_peaks<<<dim3(4, 16, 4), 256, 0, stream>>>(
            clsb, scw, cat, sc1, cat1, sc2, cat2, sc3, cat3, 20);
        k_merge4<<<256, 256, 0, stream>>>(scw, cat, sc1, cat1, sc2, cat2, sc3, cat3);
    } else {
        k_conv_fb<<<dim3(2, 128, 16), 256, 0, stream>>>(
            x, w1h, w1l, w2h, w2l, cls_b1, reg_b1, wh_b1,
            cls_b2, reg_b2, wh_b2, clsb, regb, whb);
        k_peaks<<<dim3(4, 16, 1), 256, 0, stream>>>(
            clsb, scw, cat, scw, cat, scw, cat, scw, cat, 80);
    }
    k_select<<<16, 256, 0, stream>>>(scw, cat, regb, whb, out);
}

// Round 13
// 418.412 us; speedup vs baseline: 1.3587x; 1.0215x over previous
//
#include <hip/hip_runtime.h>
#include <math.h>

// Problem constants
#define BN 16
#define HWSZ 16384
#define NC 80
#define KK 100

typedef _Float16 f16;
typedef _Float16 f16x2 __attribute__((ext_vector_type(2)));
typedef _Float16 f16x4 __attribute__((ext_vector_type(4)));
typedef _Float16 f16x8 __attribute__((ext_vector_type(8)));
typedef float    f32x4 __attribute__((ext_vector_type(4)));
typedef unsigned int uint;
typedef unsigned long long u64;

// ---- workspace layout (float units) ----
#define WS_CLS   0
#define CLS_SZ   (BN*NC*HWSZ)
#define WS_REG   (WS_CLS + CLS_SZ)
#define REG_SZ   (BN*2*HWSZ)
#define WS_WH    (WS_REG + REG_SZ)
#define WH_SZ    (BN*2*HWSZ)
#define WS_SC    (WS_WH + WH_SZ)
#define SC_SZ    (BN*HWSZ)
#define WS_CAT   (WS_SC + SC_SZ)
#define CAT_SZ   (BN*HWSZ)
#define WS_W1H   (WS_CAT + CAT_SZ)             // f16 3*9*64*64 -> 55296 floats/plane
#define W1F      (110592/2)
#define WS_W1L   (WS_W1H + W1F)
#define WS_W2H   (WS_W1L + W1F)                // f16 112*64 (padded) -> 3584 floats/plane
#define W2F      (7168/2)
#define WS_W2L   (WS_W2H + W2F)
// Pre-split/pre-transposed x in (swizzled) LDS-image layout.
// Region = (b,gy,h,chunk): 66 rows x 32ci f16 = 2112 f16 = 4224 B.
#define NREG     (BN*128*2*2)                  // 8192 regions
#define WS_XTH   (WS_W2L + W2F)
#define XT_F     (NREG*2112/2)
#define WS_XTL   (WS_XTH + XT_F)
#define WS_ZR    (WS_XTL + XT_F)               // 4224 B zero region (f16)
#define ZR_F     1056
// partial peak buffers for class-split k_peaks (eighths 1..7)
#define WS_SC1   (WS_ZR + ZR_F)
#define WS_CAT1  (WS_SC1 + SC_SZ)
#define WS_SC2   (WS_CAT1 + CAT_SZ)
#define WS_CAT2  (WS_SC2 + SC_SZ)
#define WS_SC3   (WS_CAT2 + CAT_SZ)
#define WS_CAT3  (WS_SC3 + SC_SZ)
#define WS_SC4   (WS_CAT3 + CAT_SZ)
#define WS_CAT4  (WS_SC4 + SC_SZ)
#define WS_SC5   (WS_CAT4 + CAT_SZ)
#define WS_CAT5  (WS_SC5 + SC_SZ)
#define WS_SC6   (WS_CAT5 + CAT_SZ)
#define WS_CAT6  (WS_SC6 + SC_SZ)
#define WS_SC7   (WS_CAT6 + CAT_SZ)
#define WS_CAT7  (WS_SC7 + SC_SZ)
#define WS_END8  (WS_CAT7 + CAT_SZ)

// scaling: x*16, w*256 -> acc = 4096*true
#define SCL_X   16.0f
#define SCL_W   256.0f
#define INV_ACC (1.0f/4096.0f)

// async global->LDS, 16B per lane (dest = wave-uniform base + lane*16)
#define GL2LDS(g, l) __builtin_amdgcn_global_load_lds( \
    (__attribute__((address_space(1))) unsigned int*)(unsigned long long)(const void*)(g), \
    (__attribute__((address_space(3))) unsigned int*)(unsigned int)(unsigned long long)(void*)(l), \
    16, 0, 0)

// ---------------------------------------------------------------------------
// Prep: split weights to fp16 hi/lo (scaled by 256); zero the zero-region.
// ---------------------------------------------------------------------------
__global__ void k_prep(const float* __restrict__ cw1, const float* __restrict__ rw1,
                       const float* __restrict__ ww1, const float* __restrict__ cw2,
                       const float* __restrict__ rw2, const float* __restrict__ ww2,
                       f16* __restrict__ w1h, f16* __restrict__ w1l,
                       f16* __restrict__ w2h, f16* __restrict__ w2l,
                       float* __restrict__ zr) {
    int idx = blockIdx.x * 256 + threadIdx.x;
    if (idx < 3*9*64*64) {
        int ci = idx & 63, co = (idx >> 6) & 63;
        int s  = (idx >> 12) % 9, br = idx / 36864;
        const float* src = (br == 0) ? cw1 : (br == 1 ? rw1 : ww1);
        float v = src[(co*64 + ci)*9 + s] * SCL_W;
        f16 h = (f16)v;
        w1h[idx] = h; w1l[idx] = (f16)(v - (float)h);
    }
    int j = idx - 3*9*64*64;
    if (j >= 0 && j < 112*64) {
        int ci = j & 63, row = j >> 6;
        float v = 0.f;
        if (row < 80)                    v = cw2[row*64 + ci];
        else if (row < 82)               v = rw2[(row-80)*64 + ci];
        else if (row >= 96 && row < 98)  v = ww2[(row-96)*64 + ci];
        v *= SCL_W;
        f16 h = (f16)v;
        w2h[j] = h; w2l[j] = (f16)(v - (float)h);
    }
    if (zr && idx < ZR_F) zr[idx] = 0.f;
}

// ---------------------------------------------------------------------------
// Pre-split + pre-transpose x into per-(b,gy,h,chunk) regions, with the 16B
// slot swizzle baked into the GLOBAL layout (gl2lds writes linearly, so the
// source permutation IS the LDS permutation).
// ---------------------------------------------------------------------------
__global__ __launch_bounds__(256) void k_prepx(const float* __restrict__ x,
                                               f16* __restrict__ xth,
                                               f16* __restrict__ xtl) {
    const int reg = blockIdx.x;
    const int chunk = reg & 1, hh = (reg >> 1) & 1;
    const int gy = (reg >> 2) & 127, b = reg >> 9;
    __shared__ f16 th[66*72] __attribute__((aligned(16)));
    __shared__ f16 tl[66*72] __attribute__((aligned(16)));
    const int tid = threadIdx.x;
    const float* xb = x + ((size_t)(b*64 + chunk*32))*HWSZ + gy*128;
    #pragma unroll
    for (int it = 0; it < 9; it++) {
        int idx = it*256 + tid;
        if (idx < 2112) {
            int ci = idx / 66, pxi = idx - ci*66;
            int gp = hh*64 - 1 + pxi;
            float v = 0.f;
            if (gp >= 0 && gp < 128) v = xb[(size_t)ci*HWSZ + gp] * SCL_X;
            f16 hv = (f16)v;
            th[pxi*72 + ci] = hv;
            tl[pxi*72 + ci] = (f16)(v - (float)hv);
        }
    }
    __syncthreads();
    f16* oh = xth + (size_t)reg*2112;
    f16* ol = xtl + (size_t)reg*2112;
    {
        int row = tid >> 2, q = tid & 3;
        int sq = q ^ ((row >> 1) & 3);
        *(f16x8*)(oh + row*32 + sq*8) = *(const f16x8*)(th + row*72 + q*8);
        *(f16x8*)(ol + row*32 + sq*8) = *(const f16x8*)(tl + row*72 + q*8);
        if (tid < 8) {
            int u2 = 256 + tid, row2 = u2 >> 2, q2 = u2 & 3;
            int sq2 = q2 ^ ((row2 >> 1) & 3);
            *(f16x8*)(oh + row2*32 + sq2*8) = *(const f16x8*)(th + row2*72 + q2*8);
            *(f16x8*)(ol + row2*32 + sq2*8) = *(const f16x8*)(tl + row2*72 + q2*8);
        }
    }
}

// ---------------------------------------------------------------------------
// Fused MFMA conv, r23: r22's verified 7-buffer early-staging structure
// (232 us, MfmaUtil 35.5%, zero spill) + s_setprio(1) around each MFMA
// burst (T5: 2 independent blocks/SIMD at unsynced phases -> scheduler can
// favor the MFMA-issuing wave).  Register-neutral; per-accumulator MFMA
// order identical -> bit-identical outputs.
// ---------------------------------------------------------------------------
#define ABUF 8448                    // bytes per A buffer (hi 4224 + lo 4224)
__global__ __launch_bounds__(256, 2) void k_conv(
    const f16* __restrict__ xth, const f16* __restrict__ xtl, const f16* __restrict__ zreg,
    const f16* __restrict__ w1h, const f16* __restrict__ w1l,
    const f16* __restrict__ w2h, const f16* __restrict__ w2l,
    const float* __restrict__ b1c, const float* __restrict__ b1r, const float* __restrict__ b1w,
    const float* __restrict__ b2c, const float* __restrict__ b2r, const float* __restrict__ b2w,
    float* __restrict__ cls_o, float* __restrict__ reg_o, float* __restrict__ wh_o)
{
    __shared__ char smem[7*ABUF] __attribute__((aligned(16)));   // 59136 B
    f16* Rh = (f16*)smem;                 // epilogue alias over A buffers
    f16* Rl = (f16*)(smem + 9216);

    // XCD-aware bijective swizzle (2048 % 8 == 0).
    const int p  = blockIdx.x + 2*blockIdx.y + 128*blockIdx.z;
    const int lg = (p & 7)*256 + (p >> 3);
    const int b  = lg >> 7;
    const int y0 = ((lg & 127) >> 1) * 2;      // rows y0, y0+1
    const int h  = lg & 1;

    const int tid = threadIdx.x;
    const int w = tid >> 6, lane = tid & 63;
    const int l15 = lane & 15, quad = lane >> 4;
    const int co = w*16 + l15;

    // stage one region (chunk ch, gy index gyi) into LDS buffer bufi
    #define STAGE1(ch, gyi, bufi) do {                                        \
        const int gy_ = y0 - 1 + (gyi);                                       \
        const f16* sh_; const f16* sl_;                                       \
        if (gy_ >= 0 && gy_ < 128) {                                          \
            size_t ro_ = (size_t)(((b*128 + gy_)*2 + h)*2 + (ch)) * 2112;     \
            sh_ = xth + ro_; sl_ = xtl + ro_;                                 \
        } else { sh_ = zreg; sl_ = zreg; }                                    \
        char* db_ = smem + (bufi)*ABUF;                                       \
        GL2LDS(sh_ + tid*8, db_ + tid*16);                                    \
        GL2LDS(sl_ + tid*8, db_ + 4224 + tid*16);                             \
        if (tid < 8) {                                                        \
            GL2LDS(sh_ + 2048 + tid*8, db_ + 4096 + tid*16);                  \
            GL2LDS(sl_ + 2048 + tid*8, db_ + 4224 + 4096 + tid*16);           \
        }                                                                     \
    } while (0)

    f32x4 accA[3][4], accB[3][4];
    #pragma unroll
    for (int br = 0; br < 3; br++)
        #pragma unroll
        for (int m = 0; m < 4; m++) {
            accA[br][m] = (f32x4){0.f,0.f,0.f,0.f};
            accB[br][m] = (f32x4){0.f,0.f,0.f,0.f};
        }

    // one (r,dx-sweep) step: row0 uses buffer A0, row1 uses buffer A1,
    // B fragments from chunk ph / spatial row rr.  r17's verified body,
    // with setprio(1) wrapping the MFMA+ds_read burst per dx.
    #define CSTEP(ph, rr, A0p, A1p) do {                                      \
        const f16* A0 = (const f16*)(A0p);                                    \
        const f16* A1 = (const f16*)(A1p);                                    \
        _Pragma("unroll")                                                     \
        for (int dx = 0; dx < 3; dx++) {                                      \
            const int s = (rr)*3 + dx;                                        \
            f16x8 bh[3], bl[3];                                               \
            _Pragma("unroll")                                                 \
            for (int br = 0; br < 3; br++) {                                  \
                size_t k = ((size_t)((br*9 + s)*64 + co))*64 + (ph)*32 + quad*8; \
                bh[br] = *(const f16x8*)(w1h + k);                            \
                bl[br] = *(const f16x8*)(w1l + k);                            \
            }                                                                 \
            __builtin_amdgcn_s_setprio(1);                                    \
            _Pragma("unroll")                                                 \
            for (int m = 0; m < 4; m++) {                                     \
                const int row = m*16 + l15 + dx;                              \
                const int off = row*32 + ((quad ^ ((row >> 1) & 3)) << 3);    \
                {                                                             \
                    f16x8 ah0 = *(const f16x8*)(A0 + off);                    \
                    f16x8 al0 = *(const f16x8*)(A0 + 2112 + off);             \
                    _Pragma("unroll")                                         \
                    for (int br = 0; br < 3; br++) {                          \
                        accA[br][m] = __builtin_amdgcn_mfma_f32_16x16x32_f16(ah0, bh[br], accA[br][m], 0,0,0); \
                        accA[br][m] = __builtin_amdgcn_mfma_f32_16x16x32_f16(ah0, bl[br], accA[br][m], 0,0,0); \
                        accA[br][m] = __builtin_amdgcn_mfma_f32_16x16x32_f16(al0, bh[br], accA[br][m], 0,0,0); \
                    }                                                         \
                }                                                             \
                {                                                             \
                    f16x8 ah1 = *(const f16x8*)(A1 + off);                    \
                    f16x8 al1 = *(const f16x8*)(A1 + 2112 + off);             \
                    _Pragma("unroll")                                         \
                    for (int br = 0; br < 3; br++) {                          \
                        accB[br][m] = __builtin_amdgcn_mfma_f32_16x16x32_f16(ah1, bh[br], accB[br][m], 0,0,0); \
                        accB[br][m] = __builtin_amdgcn_mfma_f32_16x16x32_f16(ah1, bl[br], accB[br][m], 0,0,0); \
                        accB[br][m] = __builtin_amdgcn_mfma_f32_16x16x32_f16(al1, bh[br], accB[br][m], 0,0,0); \
                    }                                                         \
                }                                                             \
            }                                                                 \
            __builtin_amdgcn_s_setprio(0);                                    \
        }                                                                     \
    } while (0)

    // prologue: chunk0 regions 0-3 -> bufs 0-3, chunk1 regions 0-2 -> bufs 4-6
    #pragma unroll
    for (int gyi = 0; gyi < 4; gyi++) STAGE1(0, gyi, gyi);
    #pragma unroll
    for (int gyi = 0; gyi < 3; gyi++) STAGE1(1, gyi, 4 + gyi);
    __syncthreads();        // bufs 0-6 resident

    // chunk 0 (runtime r loop, same codegen shape as r17)
    for (int r = 0; r < 3; r++)
        CSTEP(0, r, smem + r*ABUF, smem + (r+1)*ABUF);

    __syncthreads();        // chunk-0 reads done -> buffer 0 reusable
    STAGE1(1, 3, 0);        // late single region; drain covered by r=0,1 below

    // chunk 1, r = 0,1 (bufs 4,5,6 — untouched by the late stage)
    for (int r = 0; r < 2; r++)
        CSTEP(1, r, smem + (4+r)*ABUF, smem + (5+r)*ABUF);

    __syncthreads();        // buffer 0 resident (2 loads, ~2 CSTEPs old)
    CSTEP(1, 2, smem + 6*ABUF, smem + 0*ABUF);

    #undef STAGE1
    #undef CSTEP

    // ======================= epilogue: per branch x per row =======================
    #define EPIROW(ACC, yy) do {                                              \
        __syncthreads();              /* prior A/conv2 reads done */          \
        _Pragma("unroll")                                                     \
        for (int m = 0; m < 4; m++)                                           \
            _Pragma("unroll")                                                 \
            for (int rg = 0; rg < 4; rg++) {                                  \
                float t = fmaxf(ACC[br][m][rg]*INV_ACC + b1v, 0.f) * SCL_X;   \
                f16 hh = (f16)t;                                              \
                int pxl = m*16 + quad*4 + rg;                                 \
                Rh[pxl*72 + co] = hh;                                         \
                Rl[pxl*72 + co] = (f16)(t - (float)hh);                       \
            }                                                                 \
        __syncthreads();                                                      \
        const int NT     = (br == 0) ? 5 : 1;                                 \
        const int rowoff = (br == 0) ? 0 : (br == 1 ? 80 : 96);               \
        f32x4 a2[5];                                                          \
        _Pragma("unroll")                                                     \
        for (int n = 0; n < 5; n++) a2[n] = (f32x4){0.f,0.f,0.f,0.f};         \
        _Pragma("unroll")                                                     \
        for (int kc = 0; kc < 64; kc += 32) {                                 \
            int off = co*72 + kc + quad*8;                                    \
            f16x8 xh = *(const f16x8*)(Rh + off);                             \
            f16x8 xl = *(const f16x8*)(Rl + off);                             \
            _Pragma("unroll")                                                 \
            for (int n = 0; n < 5; n++) {                                     \
                if (n >= NT) break;                                           \
                const f16* g2h = w2h + (rowoff + n*16 + l15)*64 + kc + quad*8;\
                const f16* g2l = w2l + (rowoff + n*16 + l15)*64 + kc + quad*8;\
                f16x8 bh2 = *(const f16x8*)g2h;                               \
                f16x8 bl2 = *(const f16x8*)g2l;                               \
                a2[n] = __builtin_amdgcn_mfma_f32_16x16x32_f16(xh, bh2, a2[n], 0,0,0); \
                a2[n] = __builtin_amdgcn_mfma_f32_16x16x32_f16(xh, bl2, a2[n], 0,0,0); \
                a2[n] = __builtin_amdgcn_mfma_f32_16x16x32_f16(xl, bh2, a2[n], 0,0,0); \
            }                                                                 \
        }                                                                     \
        const int pxg = h*64 + w*16 + quad*4;                                 \
        if (br == 0) {                                                        \
            _Pragma("unroll")                                                 \
            for (int n = 0; n < 5; n++) {                                     \
                int co2 = n*16 + l15;                                         \
                float bb = b2c[co2];                                          \
                _Pragma("unroll")                                             \
                for (int rg = 0; rg < 4; rg++) {                              \
                    float sv = a2[n][rg]*INV_ACC + bb;                        \
                    cls_o[((size_t)(b*80 + co2)*128 + (yy))*128 + pxg + rg] = 1.f/(1.f + expf(-sv)); \
                }                                                             \
            }                                                                 \
        } else {                                                              \
            if (l15 < 2) {                                                    \
                const float* b2 = (br == 1) ? b2r : b2w;                      \
                float* outp     = (br == 1) ? reg_o : wh_o;                   \
                float bb = b2[l15];                                           \
                _Pragma("unroll")                                             \
                for (int rg = 0; rg < 4; rg++) {                              \
                    float sv = a2[0][rg]*INV_ACC + bb;                        \
                    float o  = (br == 1) ? (1.f/(1.f + expf(-sv))) : expf(sv);\
                    outp[((size_t)(b*2 + l15))*HWSZ + (yy)*128 + pxg + rg] = o; \
                }                                                             \
            }                                                                 \
        }                                                                     \
    } while (0)

    #pragma unroll
    for (int br = 0; br < 3; br++) {
        const float* b1 = (br == 0) ? b1c : (br == 1 ? b1r : b1w);
        const float b1v = b1[co];
        EPIROW(accA, y0);
        EPIROW(accB, y0 + 1);
    }
    #undef EPIROW
}

// ---------------------------------------------------------------------------
// Fallback conv (r11 kernel) — used only if ws_size can't hold the pre-split
// x planes.  Bit-identical outputs to k_conv.
// ---------------------------------------------------------------------------
#define A_STRIDE 36
#define ABUF_FB  9504
__global__ __launch_bounds__(256) void k_conv_fb(
    const float* __restrict__ x,
    const f16* __restrict__ w1h, const f16* __restrict__ w1l,
    const f16* __restrict__ w2h, const f16* __restrict__ w2l,
    const float* __restrict__ b1c, const float* __restrict__ b1r, const float* __restrict__ b1w,
    const float* __restrict__ b2c, const float* __restrict__ b2r, const float* __restrict__ b2w,
    float* __restrict__ cls_o, float* __restrict__ reg_o, float* __restrict__ wh_o)
{
    __shared__ char smem[19008] __attribute__((aligned(16)));
    f16* Rh = (f16*)smem;
    f16* Rl = (f16*)(smem + 9216);

    const int h = blockIdx.x, y = blockIdx.y, b = blockIdx.z;
    const int tid = threadIdx.x;
    const int w = tid >> 6, lane = tid & 63;
    const int l15 = lane & 15, quad = lane >> 4;

    static const int CS[6] = {0,0,0,1,1,1};
    static const int RS[6] = {0,1,2,0,1,2};

    #define STAGEF(bufi, si_) do {                                            \
        const int gy = y - 1 + RS[si_];                                       \
        const bool ok = (gy >= 0) && (gy < 128);                              \
        const float* xp = x + ((size_t)(b*64 + CS[si_]*32)*128 + gy)*128;     \
        f16x2* dh = (f16x2*)(smem + (bufi)*ABUF_FB);                          \
        f16x2* dl = (f16x2*)(smem + (bufi)*ABUF_FB + 4752);                   \
        _Pragma("unroll")                                                     \
        for (int e0 = 0; e0 < 1024; e0 += 256) {                              \
            int e = e0 + tid;                                                 \
            int pxl = e & 63, cp = e >> 6;                                    \
            float v0 = 0.f, v1 = 0.f;                                         \
            if (ok) { int g = h*64 + pxl;                                     \
                      v0 = xp[(size_t)(2*cp)*HWSZ + g]*SCL_X;                 \
                      v1 = xp[(size_t)(2*cp+1)*HWSZ + g]*SCL_X; }             \
            f16 h0 = (f16)v0, h1 = (f16)v1;                                   \
            f16 l0 = (f16)(v0 - (float)h0), l1 = (f16)(v1 - (float)h1);       \
            int wi = (pxl + 1)*18 + cp;                                       \
            dh[wi] = (f16x2){h0, h1};                                         \
            dl[wi] = (f16x2){l0, l1};                                         \
        }                                                                     \
        if (tid < 32) {                                                       \
            int side = tid >> 4, cp = tid & 15;                               \
            bool valid = ok && (side ? (h == 0) : (h == 1));                  \
            int g = side ? 64 : 63;                                           \
            float v0 = 0.f, v1 = 0.f;                                         \
            if (valid) { v0 = xp[(size_t)(2*cp)*HWSZ + g]*SCL_X;              \
                         v1 = xp[(size_t)(2*cp+1)*HWSZ + g]*SCL_X; }          \
            f16 h0 = (f16)v0, h1 = (f16)v1;                                   \
            f16 l0 = (f16)(v0 - (float)h0), l1 = (f16)(v1 - (float)h1);       \
            int wi = (side ? 65 : 0)*18 + cp;                                 \
            dh[wi] = (f16x2){h0, h1};                                         \
            dl[wi] = (f16x2){l0, l1};                                         \
        }                                                                     \
    } while (0)

    f32x4 acc[3][4];
    #pragma unroll
    for (int br = 0; br < 3; br++)
        #pragma unroll
        for (int m = 0; m < 4; m++) acc[br][m] = (f32x4){0.f,0.f,0.f,0.f};

    STAGEF(0, 0);
    __syncthreads();

    for (int si = 0; si < 6; si++) {
        const int cur = si & 1;
        if (si < 5) STAGEF(cur ^ 1, si + 1);
        const f16* APh = (const f16*)(smem + cur*ABUF_FB);
        const f16* APl = APh + 2376;
        const int chunk = CS[si], r = RS[si];
        #pragma unroll
        for (int dx = 0; dx < 3; dx++) {
            const int s = r*3 + dx;
            f16x8 bh[3], bl[3];
            #pragma unroll
            for (int br = 0; br < 3; br++) {
                size_t k = ((size_t)((br*9 + s)*64 + (w*16 + l15)))*64 + chunk*32 + quad*8;
                bh[br] = *(const f16x8*)(w1h + k);
                bl[br] = *(const f16x8*)(w1l + k);
            }
            #pragma unroll
            for (int m = 0; m < 4; m++) {
                int off = (m*16 + l15 + dx)*A_STRIDE + quad*8;
                f16x4 h0 = *(const f16x4*)(APh + off);
                f16x4 h1 = *(const f16x4*)(APh + off + 4);
                f16x4 u0 = *(const f16x4*)(APl + off);
                f16x4 u1 = *(const f16x4*)(APl + off + 4);
                f16x8 ah = __builtin_shufflevector(h0, h1, 0,1,2,3,4,5,6,7);
                f16x8 al = __builtin_shufflevector(u0, u1, 0,1,2,3,4,5,6,7);
                #pragma unroll
                for (int br = 0; br < 3; br++) {
                    acc[br][m] = __builtin_amdgcn_mfma_f32_16x16x32_f16(ah, bh[br], acc[br][m], 0,0,0);
                    acc[br][m] = __builtin_amdgcn_mfma_f32_16x16x32_f16(ah, bl[br], acc[br][m], 0,0,0);
                    acc[br][m] = __builtin_amdgcn_mfma_f32_16x16x32_f16(al, bh[br], acc[br][m], 0,0,0);
                }
            }
        }
        __syncthreads();
    }
    #undef STAGEF

    #pragma unroll
    for (int br = 0; br < 3; br++) {
        const float* b1 = (br == 0) ? b1c : (br == 1 ? b1r : b1w);
        const float b1v = b1[w*16 + l15];
        __syncthreads();
        #pragma unroll
        for (int m = 0; m < 4; m++)
            #pragma unroll
            for (int rg = 0; rg < 4; rg++) {
                float t = fmaxf(acc[br][m][rg]*INV_ACC + b1v, 0.f) * SCL_X;
                f16 hh = (f16)t;
                int pxl = m*16 + quad*4 + rg;
                int co  = w*16 + l15;
                Rh[pxl*72 + co] = hh;
                Rl[pxl*72 + co] = (f16)(t - (float)hh);
            }
        __syncthreads();

        const int NT     = (br == 0) ? 5 : 1;
        const int rowoff = (br == 0) ? 0 : (br == 1 ? 80 : 96);
        f32x4 a2[5];
        #pragma unroll
        for (int n = 0; n < 5; n++) a2[n] = (f32x4){0.f,0.f,0.f,0.f};

        #pragma unroll
        for (int kc = 0; kc < 64; kc += 32) {
            int off = (w*16 + l15)*72 + kc + quad*8;
            f16x8 xh = *(const f16x8*)(Rh + off);
            f16x8 xl = *(const f16x8*)(Rl + off);
            #pragma unroll
            for (int n = 0; n < 5; n++) {
                if (n >= NT) break;
                const f16* g2h = w2h + (rowoff + n*16 + l15)*64 + kc + quad*8;
                const f16* g2l = w2l + (rowoff + n*16 + l15)*64 + kc + quad*8;
                f16x8 bh = *(const f16x8*)g2h;
                f16x8 bl = *(const f16x8*)g2l;
                a2[n] = __builtin_amdgcn_mfma_f32_16x16x32_f16(xh, bh, a2[n], 0,0,0);
                a2[n] = __builtin_amdgcn_mfma_f32_16x16x32_f16(xh, bl, a2[n], 0,0,0);
                a2[n] = __builtin_amdgcn_mfma_f32_16x16x32_f16(xl, bh, a2[n], 0,0,0);
            }
        }

        const int pxg = h*64 + w*16 + quad*4;
        if (br == 0) {
            #pragma unroll
            for (int n = 0; n < 5; n++) {
                int co2 = n*16 + l15;
                float bb = b2c[co2];
                #pragma unroll
                for (int rg = 0; rg < 4; rg++) {
                    float sv = a2[n][rg]*INV_ACC + bb;
                    cls_o[((size_t)(b*80 + co2)*128 + y)*128 + pxg + rg] = 1.f/(1.f + expf(-sv));
                }
            }
        } else {
            if (l15 < 2) {
                const float* b2 = (br == 1) ? b2r : b2w;
                float* outp     = (br == 1) ? reg_o : wh_o;
                float bb = b2[l15];
                #pragma unroll
                for (int rg = 0; rg < 4; rg++) {
                    float sv = a2[0][rg]*INV_ACC + bb;
                    float o  = (br == 1) ? (1.f/(1.f + expf(-sv))) : expf(sv);
                    outp[((size_t)(b*2 + l15))*HWSZ + y*128 + pxg + rg] = o;
                }
            }
        }
    }
}

// ---------------------------------------------------------------------------
// 3x3 peak mask + max/argmax over a CLASS RANGE, r23: back to 4 rows/wave
// (r22's 8-row cut blocks to 1/CU and regressed ~5us — latency-bound), with
// an 8-way class split (span 10) for 1024 blocks = 4/CU.  fmax order per
// row preserved exactly -> bit-identical after ordered merge.
// grid (8, 16, 8) span 10; fallback (8, 16, 1) span 80.
// ---------------------------------------------------------------------------
__global__ __launch_bounds__(256) void k_peaks(const float* __restrict__ cls,
                                               float* __restrict__ s0, int* __restrict__ c0p,
                                               float* __restrict__ s1, int* __restrict__ c1p,
                                               float* __restrict__ s2, int* __restrict__ c2p,
                                               float* __restrict__ s3, int* __restrict__ c3p,
                                               float* __restrict__ s4, int* __restrict__ c4p,
                                               float* __restrict__ s5, int* __restrict__ c5p,
                                               float* __restrict__ s6, int* __restrict__ c6p,
                                               float* __restrict__ s7, int* __restrict__ c7p,
                                               int span) {
    const int b  = blockIdx.y;
    const int z  = blockIdx.z;
    const int c0 = z * span, c1 = c0 + span;
    float* __restrict__ sc  = (z == 0) ? s0 : (z == 1) ? s1 : (z == 2) ? s2 : (z == 3) ? s3
                            : (z == 4) ? s4 : (z == 5) ? s5 : (z == 6) ? s6 : s7;
    int*   __restrict__ cat = (z == 0) ? c0p : (z == 1) ? c1p : (z == 2) ? c2p : (z == 3) ? c3p
                            : (z == 4) ? c4p : (z == 5) ? c5p : (z == 6) ? c6p : c7p;
    const int wv = threadIdx.x >> 6;
    const int l  = threadIdx.x & 63;
    const int y0 = blockIdx.x * 16 + wv * 4;    // rows y0 .. y0+3
    const int p0 = l * 2;
    const bool gt = (y0 > 0);
    const bool gb = (y0 + 4 < 128);
    float best[8]; int bc[8];
    #pragma unroll
    for (int i = 0; i < 8; i++) { best[i] = -1.f; bc[i] = c0; }
    for (int c = c0; c < c1; c++) {
        const float* pl = cls + (size_t)(b*80 + c)*HWSZ + y0*128 + p0;
        float2 t[6];
        t[0] = gt ? *(const float2*)(pl - 128) : make_float2(-1e30f, -1e30f);
        t[1] = *(const float2*)pl;
        t[2] = *(const float2*)(pl + 128);
        t[3] = *(const float2*)(pl + 256);
        t[4] = *(const float2*)(pl + 384);
        t[5] = gb ? *(const float2*)(pl + 512) : make_float2(-1e30f, -1e30f);
        #pragma unroll
        for (int i = 0; i < 4; i++) {
            // row y0+i: cur=t[i+1], tp=t[i], bt=t[i+2] — same fmax order
            float vm0 = fmaxf(t[i+1].x, fmaxf(t[i].x, t[i+2].x));
            float vm1 = fmaxf(t[i+1].y, fmaxf(t[i].y, t[i+2].y));
            float lft = __shfl_up(vm1, 1);   if (l == 0)  lft = -1e30f;
            float rgt = __shfl_down(vm0, 1); if (l == 63) rgt = -1e30f;
            float m0 = fmaxf(lft, fmaxf(vm0, vm1));
            float m1 = fmaxf(vm0, fmaxf(vm1, rgt));
            float k0 = (t[i+1].x == m0) ? t[i+1].x : 0.f;
            float k1 = (t[i+1].y == m1) ? t[i+1].y : 0.f;
            if (k0 > best[2*i])   { best[2*i]   = k0; bc[2*i]   = c; }
            if (k1 > best[2*i+1]) { best[2*i+1] = k1; bc[2*i+1] = c; }
        }
    }
    #pragma unroll
    for (int i = 0; i < 4; i++) {
        int o = b*HWSZ + (y0 + i)*128 + p0;
        *(float2*)&sc[o] = make_float2(best[2*i], best[2*i+1]);
        *(int2*)&cat[o]  = make_int2(bc[2*i], bc[2*i+1]);
    }
}

// ---------------------------------------------------------------------------
// Merge the 8 class-eighth partials into sc0/cat0 in place.  Sequential
// strict-> merges in ascending range order -> lowest class index wins ties,
// reproducing the full argmax exactly.
// ---------------------------------------------------------------------------
__global__ __launch_bounds__(256) void k_merge8(
        float* __restrict__ d0, int* __restrict__ e0,
        const float* __restrict__ s1, const int* __restrict__ c1,
        const float* __restrict__ s2, const int* __restrict__ c2,
        const float* __restrict__ s3, const int* __restrict__ c3,
        const float* __restrict__ s4, const int* __restrict__ c4,
        const float* __restrict__ s5, const int* __restrict__ c5,
        const float* __restrict__ s6, const int* __restrict__ c6,
        const float* __restrict__ s7, const int* __restrict__ c7) {
    int i = (blockIdx.x * 256 + threadIdx.x) * 4;      // 262144 elems, grid 256
    float4 a = *(const float4*)(d0 + i);
    int4   ca = *(const int4*)(e0 + i);
    #define MRG(SS, CC) do {                                                  \
        float4 bq = *(const float4*)((SS) + i);                               \
        int4   cb = *(const int4*)((CC) + i);                                 \
        if (bq.x > a.x) { a.x = bq.x; ca.x = cb.x; }                          \
        if (bq.y > a.y) { a.y = bq.y; ca.y = cb.y; }                          \
        if (bq.z > a.z) { a.z = bq.z; ca.z = cb.z; }                          \
        if (bq.w > a.w) { a.w = bq.w; ca.w = cb.w; }                          \
    } while (0)
    MRG(s1, c1); MRG(s2, c2); MRG(s3, c3); MRG(s4, c4);
    MRG(s5, c5); MRG(s6, c6); MRG(s7, c7);
    #undef MRG
    *(float4*)(d0 + i) = a;
    *(int4*)(e0 + i)  = ca;
}

// ---------------------------------------------------------------------------
// k_select (verified r14): top-100 via integer bisection on float bits,
// deterministic index-ordered collect, 128-wide bitonic sort on
// (~valbits, idx) == (value desc, index asc) — exactly lax.top_k's order.
// Then box decode + NMS.
// ---------------------------------------------------------------------------
__global__ __launch_bounds__(256) void k_select(const float* __restrict__ sc,
                                                const int* __restrict__ cats,
                                                const float* __restrict__ regp,
                                                const float* __restrict__ whp,
                                                float* __restrict__ out) {
    const int b   = blockIdx.x;
    const int tid = threadIdx.x;
    const int wv  = tid >> 6, lane = tid & 63;
    const float* scb = sc + (size_t)b*HWSZ;

    __shared__ int   red[2][4];
    __shared__ uint  wtot[4];
    __shared__ int   gib[128];
    __shared__ uint  gvb[128];
    __shared__ int   ebuf[KK];
    __shared__ u64   keys[128];
    __shared__ int   s_inds[KK];
    __shared__ float s_vals[KK];
    __shared__ float X1[KK], Y1[KK], X2[KK], Y2[KK], AR[KK];

    f32x4 d[16];
    #pragma unroll
    for (int c = 0; c < 16; c++)
        d[c] = *(const f32x4*)(scb + c*1024 + tid*4);

    #define CNT_GT(T, OUTV) do {                                              \
        int myc_ = 0;                                                         \
        _Pragma("unroll")                                                     \
        for (int c = 0; c < 16; c++) {                                        \
            _Pragma("unroll")                                                 \
            for (int j = 0; j < 4; j++)                                       \
                myc_ += (__float_as_uint(d[c][j]) > (T)) ? 1 : 0;             \
        }                                                                     \
        _Pragma("unroll")                                                     \
        for (int o_ = 32; o_ >= 1; o_ >>= 1) myc_ += __shfl_xor(myc_, o_);    \
        if (lane == 0) red[par][wv] = myc_;                                   \
        __syncthreads();                                                      \
        OUTV = red[par][0] + red[par][1] + red[par][2] + red[par][3];         \
        par ^= 1;                                                             \
    } while (0)

    int par = 0;
    uint Vbits; uint G;
    {
        int tot0; CNT_GT(0u, tot0);
        if (tot0 < KK) { Vbits = 0u; G = (uint)tot0; }
        else {
            uint lo = 0u, hi = 0x7F800000u; int gHi = 0;
            while (hi - lo > 1u) {
                uint mid = lo + ((hi - lo) >> 1);
                int t_; CNT_GT(mid, t_);
                if (t_ >= KK) lo = mid; else { hi = mid; gHi = t_; }
            }
            Vbits = hi; G = (uint)gHi;
        }
    }
    #undef CNT_GT
    const uint Eneed = KK - G;

    f32x4 c4[16];
    #pragma unroll
    for (int c = 0; c < 16; c++)
        c4[c] = *(const f32x4*)(scb + tid*64 + c*4);

    uint cntG = 0, cntE = 0;
    #pragma unroll
    for (int c = 0; c < 16; c++)
        #pragma unroll
        for (int j = 0; j < 4; j++) {
            uint u = __float_as_uint(c4[c][j]);
            cntG += (u > Vbits) ? 1u : 0u;
            cntE += (u == Vbits) ? 1u : 0u;
        }
    uint pk = (cntE << 16) | cntG;
    uint v = pk;
    #pragma unroll
    for (int o = 1; o <= 32; o <<= 1) {
        uint ov = __shfl_up(v, o);
        if (lane >= o) v += ov;
    }
    if (lane == 63) wtot[wv] = v;
    __syncthreads();
    uint woff = 0;
    for (int i = 0; i < 4; i++) if (i < wv) woff += wtot[i];
    uint excl = v - pk + woff;
    uint pG = excl & 0xFFFFu, pE = excl >> 16;

    #pragma unroll
    for (int c = 0; c < 16; c++)
        #pragma unroll
        for (int j = 0; j < 4; j++) {
            uint u = __float_as_uint(c4[c][j]);
            int idx = tid*64 + c*4 + j;
            if (u > Vbits) { gib[pG] = idx; gvb[pG] = u; pG++; }
            else if (u == Vbits) { if (pE < Eneed) ebuf[pE] = idx; pE++; }
        }
    __syncthreads();

    if (tid < 128)
        keys[tid] = (tid < (int)G) ? (((u64)(~gvb[tid]) << 32) | (uint)gib[tid])
                                   : ~0ull;
    for (uint k2 = 2; k2 <= 128; k2 <<= 1) {
        for (uint j = k2 >> 1; j > 0; j >>= 1) {
            __syncthreads();
            if (tid < 128) {
                uint i = (uint)tid, ixj = i ^ j;
                if (ixj > i) {
                    u64 a = keys[i], bb = keys[ixj];
                    bool up = ((i & k2) == 0);
                    if ((a > bb) == up) { keys[i] = bb; keys[ixj] = a; }
                }
            }
        }
    }
    __syncthreads();

    if (tid < KK) {
        if (tid < (int)G) {
            u64 kk2 = keys[tid];
            s_inds[tid] = (int)(uint)kk2;
            s_vals[tid] = __uint_as_float(~(uint)(kk2 >> 32));
        } else {
            s_inds[tid] = ebuf[tid - (int)G];
            s_vals[tid] = __uint_as_float(Vbits);
        }
    }
    __syncthreads();

    if (tid < KK) {  // decode boxes
        int ind   = s_inds[tid];
        float scv = s_vals[tid];
        const float* rb = regp + (size_t)b*2*HWSZ;
        const float* wb = whp  + (size_t)b*2*HWSZ;
        float r0 = rb[ind], r1 = rb[HWSZ + ind];
        float w0 = wb[ind], w1 = wb[HWSZ + ind];
        float ctx = (float)(ind & 127) + r0;
        float cty = (float)(ind >> 7) + r1;
        float x1 = (ctx - w0*0.5f)*4.f, y1 = (cty - w1*0.5f)*4.f;
        float x2 = (ctx + w0*0.5f)*4.f, y2 = (cty + w1*0.5f)*4.f;
        size_t bo = ((size_t)b*KK + tid)*4;
        out[bo+0] = x1; out[bo+1] = y1; out[bo+2] = x2; out[bo+3] = y2;
        out[BN*KK*4 + b*KK + tid]         = (float)cats[(size_t)b*HWSZ + ind];
        out[BN*KK*4 + BN*KK + b*KK + tid] = scv;
        X1[tid] = x1; Y1[tid] = y1; X2[tid] = x2; Y2[tid] = y2;
        AR[tid] = (x2 - x1)*(y2 - y1);
    }
    __syncthreads();

    if (tid < 64) {  // NMS in wave 0
        const int l = tid;
        float x1a = X1[l], y1a = Y1[l], x2a = X2[l], y2a = Y2[l], ara = AR[l];
        int   ka  = (s_vals[l] > 0.2f) ? 1 : 0;
        float x1b = 0, y1b = 0, x2b = 0, y2b = 0, arb = 0;
        int   kb  = 0;
        if (l < KK - 64) {
            x1b = X1[64+l]; y1b = Y1[64+l]; x2b = X2[64+l]; y2b = Y2[64+l];
            arb = AR[64+l];
            kb  = (s_vals[64+l] > 0.2f) ? 1 : 0;
        }
        for (int i = 0; i < KK; i++) {
            float jx1, jy1, jx2, jy2, jar; int jk;
            if (i < 64) {
                jx1 = __shfl(x1a, i); jy1 = __shfl(y1a, i);
                jx2 = __shfl(x2a, i); jy2 = __shfl(y2a, i);
                jar = __shfl(ara, i); jk  = __shfl(ka,  i);
            } else {
                int li = i - 64;
                jx1 = __shfl(x1b, li); jy1 = __shfl(y1b, li);
                jx2 = __shfl(x2b, li); jy2 = __shfl(y2b, li);
                jar = __shfl(arb, li); jk  = __shfl(kb,  li);
            }
            if (jk) {
                if (ka && l > i) {
                    float iw = fminf(jx2, x2a) - fmaxf(jx1, x1a); iw = iw > 0.f ? iw : 0.f;
                    float ih = fminf(jy2, y2a) - fmaxf(jy1, y1a); ih = ih > 0.f ? ih : 0.f;
                    float inter = iw*ih;
                    float iou = inter / (jar + ara - inter + 1e-9f);
                    if (iou > 0.5f) ka = 0;
                }
                if (kb && (64 + l) > i) {
                    float iw = fminf(jx2, x2b) - fmaxf(jx1, x1b); iw = iw > 0.f ? iw : 0.f;
                    float ih = fminf(jy2, y2b) - fmaxf(jy1, y1b); ih = ih > 0.f ? ih : 0.f;
                    float inter = iw*ih;
                    float iou = inter / (jar + arb - inter + 1e-9f);
                    if (iou > 0.5f) kb = 0;
                }
            }
        }
        int koff = BN*KK*4 + 2*BN*KK;
        out[koff + b*KK + l] = ka ? 1.f : 0.f;
        if (l < KK - 64) out[koff + b*KK + 64 + l] = kb ? 1.f : 0.f;
    }
}

// ---------------------------------------------------------------------------
extern "C" void kernel_launch(void* const* d_in, const int* in_sizes, int n_in,
                              void* d_out, int out_size, void* d_ws, size_t ws_size,
                              hipStream_t stream) {
    const float* x      = (const float*)d_in[0];
    const float* cls_w1 = (const float*)d_in[1];
    const float* cls_b1 = (const float*)d_in[2];
    const float* cls_w2 = (const float*)d_in[3];
    const float* cls_b2 = (const float*)d_in[4];
    const float* reg_w1 = (const float*)d_in[5];
    const float* reg_b1 = (const float*)d_in[6];
    const float* reg_w2 = (const float*)d_in[7];
    const float* reg_b2 = (const float*)d_in[8];
    const float* wh_w1  = (const float*)d_in[9];
    const float* wh_b1  = (const float*)d_in[10];
    const float* wh_w2  = (const float*)d_in[11];
    const float* wh_b2  = (const float*)d_in[12];

    float* ws   = (float*)d_ws;
    float* clsb = ws + WS_CLS;
    float* regb = ws + WS_REG;
    float* whb  = ws + WS_WH;
    float* scw  = ws + WS_SC;
    int*   cat  = (int*)(ws + WS_CAT);
    f16*   w1h  = (f16*)(ws + WS_W1H);
    f16*   w1l  = (f16*)(ws + WS_W1L);
    f16*   w2h  = (f16*)(ws + WS_W2H);
    f16*   w2l  = (f16*)(ws + WS_W2L);
    f16*   xth  = (f16*)(ws + WS_XTH);
    f16*   xtl  = (f16*)(ws + WS_XTL);
    f16*   zr   = (f16*)(ws + WS_ZR);
    float* out  = (float*)d_out;

    const bool big = ws_size >= (size_t)WS_END8 * 4u;

    k_prep<<<(3*9*64*64 + 112*64 + 255)/256, 256, 0, stream>>>(
        cls_w1, reg_w1, wh_w1, cls_w2, reg_w2, wh_w2, w1h, w1l, w2h, w2l,
        big ? (float*)(ws + WS_ZR) : (float*)0);
    if (big) {
        float* s1 = ws + WS_SC1;  int* c1 = (int*)(ws + WS_CAT1);
        float* s2 = ws + WS_SC2;  int* c2 = (int*)(ws + WS_CAT2);
        float* s3 = ws + WS_SC3;  int* c3 = (int*)(ws + WS_CAT3);
        float* s4 = ws + WS_SC4;  int* c4 = (int*)(ws + WS_CAT4);
        float* s5 = ws + WS_SC5;  int* c5 = (int*)(ws + WS_CAT5);
        float* s6 = ws + WS_SC6;  int* c6 = (int*)(ws + WS_CAT6);
        float* s7 = ws + WS_SC7;  int* c7 = (int*)(ws + WS_CAT7);
        k_prepx<<<NREG, 256, 0, stream>>>(x, xth, xtl);
        k_conv<<<dim3(2, 64, 16), 256, 0, stream>>>(
            xth, xtl, zr, w1h, w1l, w2h, w2l, cls_b1, reg_b1, wh_b1,
            cls_b2, reg_b2, wh_b2, clsb, regb, whb);
        k_peaks<<<dim3(8, 16, 8), 256, 0, stream>>>(
            clsb, scw, cat, s1, c1, s2, c2, s3, c3, s4, c4, s5, c5, s6, c6, s7, c7, 10);
        k_merge8<<<256, 256, 0, stream>>>(
            scw, cat, s1, c1, s2, c2, s3, c3, s4, c4, s5, c5, s6, c6, s7, c7);
    } else {
        k_conv_fb<<<dim3(2, 128, 16), 256, 0, stream>>>(
            x, w1h, w1l, w2h, w2l, cls_b1, reg_b1, wh_b1,
            cls_b2, reg_b2, wh_b2, clsb, regb, whb);
        k_peaks<<<dim3(8, 16, 1), 256, 0, stream>>>(
            clsb, scw, cat, scw, cat, scw, cat, scw, cat,
            scw, cat, scw, cat, scw, cat, scw, cat, 80);
    }
    k_select<<<16, 256, 0, stream>>>(scw, cat, regb, whb, out);
}